// Round 9
// baseline (231.767 us; speedup 1.0000x reference)
//
#include <hip/hip_runtime.h>
#include <hip/hip_bf16.h>
#include <stdint.h>

#define D_MODEL 1024
#define NHEAD 16
#define SEQ 2048
#define BATCH 4
#define DK 64
#define QKVSTR 3072

typedef __attribute__((ext_vector_type(8))) short short8;
typedef __attribute__((ext_vector_type(4))) float f32x4;

#if __has_builtin(__builtin_amdgcn_exp2f)
#define EXP2(x) __builtin_amdgcn_exp2f(x)
#else
#define EXP2(x) exp2f(x)
#endif

__device__ inline unsigned short f2bf(float f) {
  unsigned int u = __builtin_bit_cast(unsigned int, f);
  unsigned int r = (u + 0x7fffu + ((u >> 16) & 1u)) >> 16;
  return (unsigned short)r;
}

#define GLOAD_LDS16(g, l) \
  __builtin_amdgcn_global_load_lds((const __attribute__((address_space(1))) unsigned int*)(g), \
      (__attribute__((address_space(3))) unsigned int*)(l), 16, 0, 0)

// ---------------- f32 -> bf16 convert ----------------
__global__ void cvt_kernel(const float* __restrict__ in, unsigned short* __restrict__ out, int n) {
  int i = (blockIdx.x * 256 + threadIdx.x) * 8;
  if (i >= n) return;
  const float4* p = (const float4*)(in + i);
  float4 a = p[0], b = p[1];
  union { unsigned short u[8]; uint4 v; } r;
  r.u[0] = f2bf(a.x); r.u[1] = f2bf(a.y); r.u[2] = f2bf(a.z); r.u[3] = f2bf(a.w);
  r.u[4] = f2bf(b.x); r.u[5] = f2bf(b.y); r.u[6] = f2bf(b.z); r.u[7] = f2bf(b.w);
  *(uint4*)(out + i) = r.v;
}

// 4 weight matrices in one dispatch; outputs contiguous at out + by*n
__global__ void cvt4_kernel(const float* __restrict__ i0, const float* __restrict__ i1,
                            const float* __restrict__ i2, const float* __restrict__ i3,
                            unsigned short* __restrict__ out, int n) {
  const int by = blockIdx.y;
  const float* in = (by == 0) ? i0 : (by == 1) ? i1 : (by == 2) ? i2 : i3;
  unsigned short* o = out + (size_t)by * n;
  int i = (blockIdx.x * 256 + threadIdx.x) * 8;
  if (i >= n) return;
  const float4* p = (const float4*)(in + i);
  float4 a = p[0], b = p[1];
  union { unsigned short u[8]; uint4 v; } r;
  r.u[0] = f2bf(a.x); r.u[1] = f2bf(a.y); r.u[2] = f2bf(a.z); r.u[3] = f2bf(a.w);
  r.u[4] = f2bf(b.x); r.u[5] = f2bf(b.y); r.u[6] = f2bf(b.z); r.u[7] = f2bf(b.w);
  *(uint4*)(o + i) = r.v;
}

// ---------------- GEMM: C[M,N] = f(A[M,K] * B[N,K]^T + bias) ----------------
// bias selected per 1024-column section from b0/b1/b2; cols < qcols scaled by alphaQ.
template <typename CT>
__global__ __launch_bounds__(256)
void gemm_bt(const unsigned short* __restrict__ A, const unsigned short* __restrict__ B,
             const float* __restrict__ b0, const float* __restrict__ b1,
             const float* __restrict__ b2, CT* __restrict__ C, int M, int N, int K,
             int qcols, float alphaQ) {
  __shared__ unsigned short As[128 * 64];
  __shared__ unsigned short Bs[128 * 64];
  const int t = threadIdx.x;
  const int l = t & 63;
  const int w = t >> 6;
  const int wr = w >> 1, wc = w & 1;
  const int l15 = l & 15, lg = l >> 4;
  const int m0 = blockIdx.y * 128, n0 = blockIdx.x * 128;

  f32x4 acc[4][4] = {};

  const int srow = t >> 3;       // 0..31
  const int scol = (t & 7) * 8;  // 0..56

  for (int k0 = 0; k0 < K; k0 += 64) {
    #pragma unroll
    for (int i = 0; i < 4; ++i) {
      GLOAD_LDS16(A + (size_t)(m0 + i * 32 + srow) * K + k0 + scol, &As[(i * 32 + srow) * 64 + scol]);
      GLOAD_LDS16(B + (size_t)(n0 + i * 32 + srow) * K + k0 + scol, &Bs[(i * 32 + srow) * 64 + scol]);
    }
    __syncthreads();
    #pragma unroll
    for (int kk = 0; kk < 2; ++kk) {
      short8 af[4], bfr[4];
      #pragma unroll
      for (int m = 0; m < 4; ++m)
        af[m] = *(const short8*)&As[(wr * 64 + m * 16 + l15) * 64 + kk * 32 + lg * 8];
      #pragma unroll
      for (int n = 0; n < 4; ++n)
        bfr[n] = *(const short8*)&Bs[(wc * 64 + n * 16 + l15) * 64 + kk * 32 + lg * 8];
      #pragma unroll
      for (int m = 0; m < 4; ++m)
        #pragma unroll
        for (int n = 0; n < 4; ++n)
          acc[m][n] = __builtin_amdgcn_mfma_f32_16x16x32_bf16(af[m], bfr[n], acc[m][n], 0, 0, 0);
    }
    __syncthreads();
  }

  #pragma unroll
  for (int m = 0; m < 4; ++m) {
    #pragma unroll
    for (int n = 0; n < 4; ++n) {
      int col = n0 + wc * 64 + n * 16 + l15;
      const float* bp = (col < 1024) ? b0 : (col < 2048) ? b1 : b2;
      float bz = bp[col & 1023];
      #pragma unroll
      for (int r = 0; r < 4; ++r) {
        int row = m0 + wr * 64 + m * 16 + lg * 4 + r;
        float v = acc[m][n][r] + bz;
        if (col < qcols) v *= alphaQ;
        if constexpr (sizeof(CT) == 2) {
          C[(size_t)row * N + col] = (CT)f2bf(v);
        } else {
          C[(size_t)row * N + col] = v;
        }
      }
    }
  }
}

// ---------------- causal flash attention: KVBLK=128, paired q-tiles, swapped QK^T ----------------
// QKV: [B*S, 3072] bf16 rows = [Q | K | V], head h at col h*64 within each section.
// Q pre-scaled by 0.125*log2(e); softmax in exp2 domain.
// S^T via mfma(K,Q): lane owns q=l15; kv = n*16 + lg*4 + r, n=0..7 over 128 kv.
// Merged QK: each K fragment read once, feeds both q-tiles.
// V(t+1) register prefetch kept in flight across barrier#2 via counted vmcnt(4).
__global__ __launch_bounds__(256, 3)
void attn_kernel(const unsigned short* __restrict__ QKV, unsigned short* __restrict__ AO) {
  __shared__ unsigned short Ks[128 * 64];      // K tile, swizzled chunks
  __shared__ unsigned int Vt32[64 * 66];       // [d][kv-pair] packed 2xbf16; stride 66 (2 mod 32)
  __shared__ unsigned short Pl[4][16][136];    // per-wave P: [q][128 kv]

  const int t = threadIdx.x;
  const int l = t & 63;
  const int w = t >> 6;
  const int l15 = l & 15, lg = l >> 4;
  const int id = blockIdx.x;
  const int i = id >> 6;        // 0..15
  const int bh = id & 63;       // same-head blocks differ by 64 -> same XCD
  const int qtA = 31 - i;       // long q-tile
  const int qtB = i;            // short q-tile
  const int b = bh >> 4, h = bh & 15;
  const size_t hbase = (size_t)b * SEQ * QKVSTR + h * DK;
  const size_t hbaseO = (size_t)b * SEQ * D_MODEL + h * DK;

  // hoisted Q fragments for both q-tiles (MFMA B-operand)
  short8 qfA[2], qfB[2];
  {
    const unsigned short* qp = QKV + hbase + (size_t)(qtA * 64 + w * 16 + l15) * QKVSTR + lg * 8;
    qfA[0] = *(const short8*)qp; qfA[1] = *(const short8*)(qp + 32);
    qp = QKV + hbase + (size_t)(qtB * 64 + w * 16 + l15) * QKVSTR + lg * 8;
    qfB[0] = *(const short8*)qp; qfB[1] = *(const short8*)(qp + 32);
  }

  f32x4 oA[4] = {}, oB[4] = {};
  float laccA = 0.f, laccB = 0.f;
  float mA = -INFINITY, mB = -INFINITY;

  // K staging map: thread t covers row srow(+32j), 16B chunk sc8; source chunk XOR-swizzled
  const int srow = t >> 3, sc8 = t & 7;
  const int kssw = sc8 ^ (srow & 7);
  // V staging map: thread t covers kv pair, 16 d values
  const int vpair = (t & 31) + ((t >> 7) << 5);   // 0..63
  const int vdh = ((t >> 5) & 3) * 16;            // d base 0/16/32/48
  const int qrowbase = w * 16 + lg * 4;

  // softmax over 128 kv (S^T layout): q=l15 scalar stats; P -> Pl; returns pa frags (4x short8)
  auto softmax_upd = [&](f32x4 (&s)[8], float& m, float& lacc, f32x4 (&o)[4],
                         bool diag, int qt, int kv0, short8 (&pa)[4]) {
    const int q = qt * 64 + w * 16 + l15;
    if (diag) {
      #pragma unroll
      for (int n = 0; n < 8; ++n)
        #pragma unroll
        for (int r = 0; r < 4; ++r)
          if (kv0 + n * 16 + lg * 4 + r > q) s[n][r] = -INFINITY;
    }
    float pm = -INFINITY;
    #pragma unroll
    for (int n = 0; n < 8; ++n)
      #pragma unroll
      for (int r = 0; r < 4; ++r) pm = fmaxf(pm, s[n][r]);
    pm = fmaxf(pm, __shfl_xor(pm, 16, 64));
    pm = fmaxf(pm, __shfl_xor(pm, 32, 64));
    float mx = fmaxf(m, pm);
    if (!__all(mx - m <= 11.0f)) {       // defer-max: rescale only on real growth
      float al = EXP2(m - mx);
      m = mx;
      lacc *= al;
      float alo[4];
      #pragma unroll
      for (int r = 0; r < 4; ++r) alo[r] = __shfl(al, lg * 4 + r, 64);
      #pragma unroll
      for (int n = 0; n < 4; ++n)
        #pragma unroll
        for (int r = 0; r < 4; ++r) o[n][r] *= alo[r];
    }
    float ps = 0.f;
    #pragma unroll
    for (int n = 0; n < 8; ++n) {
      float p0 = EXP2(s[n][0] - m), p1 = EXP2(s[n][1] - m);
      float p2 = EXP2(s[n][2] - m), p3 = EXP2(s[n][3] - m);
      ps += (p0 + p1) + (p2 + p3);
      unsigned int d0 = (unsigned int)f2bf(p0) | ((unsigned int)f2bf(p1) << 16);
      unsigned int d1 = (unsigned int)f2bf(p2) | ((unsigned int)f2bf(p3) << 16);
      *(uint2*)&Pl[w][l15][n * 16 + lg * 4] = make_uint2(d0, d1);
    }
    ps += __shfl_xor(ps, 16, 64);
    ps += __shfl_xor(ps, 32, 64);
    lacc += ps;
    #pragma unroll
    for (int ks = 0; ks < 4; ++ks)
      pa[ks] = *(const short8*)&Pl[w][l15][ks * 32 + lg * 8];
  };

  const int ntiles = (qtA >> 1) + 1;     // 128-kv iterations
  const int lastB = qtB >> 1;
  const unsigned short* vbase = QKV + hbase + 2048;

  // prologue: V(0) register loads in flight
  short8 cv0, cv1, cv2, cv3;
  {
    const unsigned short* vp = vbase + (size_t)(2 * vpair) * QKVSTR + vdh;
    cv0 = *(const short8*)vp;
    cv1 = *(const short8*)(vp + 8);
    cv2 = *(const short8*)(vp + QKVSTR);
    cv3 = *(const short8*)(vp + QKVSTR + 8);
  }

  for (int kvt = 0; kvt < ntiles; ++kvt) {
    const int kv0 = kvt * 128;
    // barrier#1: all waves done reading Ks/Vt of previous iteration
    __builtin_amdgcn_s_barrier();
    asm volatile("s_waitcnt vmcnt(0)" ::: "memory");   // V(t) regs arrived
    __builtin_amdgcn_sched_barrier(0);

    // stage V(t): packed transpose, 16 ds_write_b32
    #pragma unroll
    for (int j = 0; j < 8; ++j) {
      Vt32[(vdh + j) * 66 + vpair] =
          (unsigned int)(unsigned short)cv0[j] | ((unsigned int)(unsigned short)cv2[j] << 16);
      Vt32[(vdh + 8 + j) * 66 + vpair] =
          (unsigned int)(unsigned short)cv1[j] | ((unsigned int)(unsigned short)cv3[j] << 16);
    }
    // K(t): 4 async DMA (issued BEFORE the V prefetch so vmcnt(4) drains exactly these)
    {
      const unsigned short* kp = QKV + hbase + 1024 + (size_t)(kv0 + srow) * QKVSTR + kssw * 8;
      #pragma unroll
      for (int j = 0; j < 4; ++j)
        GLOAD_LDS16(kp + (size_t)(32 * j) * QKVSTR, &Ks[(j * 32 + srow) * 64 + sc8 * 8]);
    }
    // V(t+1) register prefetch (safe address on last iter)
    {
      const int nk = (kvt + 1 < ntiles) ? kv0 + 128 : 0;
      const unsigned short* vp = vbase + (size_t)(nk + 2 * vpair) * QKVSTR + vdh;
      short8 nv0 = *(const short8*)vp;
      short8 nv1 = *(const short8*)(vp + 8);
      short8 nv2 = *(const short8*)(vp + QKVSTR);
      short8 nv3 = *(const short8*)(vp + QKVSTR + 8);
      // barrier#2: K DMA drained (vmcnt(4) leaves the 4 nv loads in flight), Vt writes visible
      asm volatile("s_waitcnt vmcnt(4) lgkmcnt(0)" ::: "memory");
      __builtin_amdgcn_s_barrier();
      __builtin_amdgcn_sched_barrier(0);

      const bool bAct = (kvt <= lastB);
      short8 paA[4], paB[4];
      f32x4 sA[8], sB[8];

      // ---- merged swapped QK^T: each K fragment read once, used for both q-tiles ----
      __builtin_amdgcn_s_setprio(1);
      #pragma unroll
      for (int n = 0; n < 8; ++n) {
        int row = n * 16 + l15;
        short8 kf0 = *(const short8*)&Ks[row * 64 + ((lg ^ (row & 7)) * 8)];
        short8 kf1 = *(const short8*)&Ks[row * 64 + (((4 + lg) ^ (row & 7)) * 8)];
        f32x4 z = {};
        z = __builtin_amdgcn_mfma_f32_16x16x32_bf16(kf0, qfA[0], z, 0, 0, 0);
        z = __builtin_amdgcn_mfma_f32_16x16x32_bf16(kf1, qfA[1], z, 0, 0, 0);
        sA[n] = z;
        if (bAct) {
          f32x4 y = {};
          y = __builtin_amdgcn_mfma_f32_16x16x32_bf16(kf0, qfB[0], y, 0, 0, 0);
          y = __builtin_amdgcn_mfma_f32_16x16x32_bf16(kf1, qfB[1], y, 0, 0, 0);
          sB[n] = y;
        }
      }
      __builtin_amdgcn_s_setprio(0);

      softmax_upd(sA, mA, laccA, oA, kvt == ntiles - 1, qtA, kv0, paA);
      if (bAct) softmax_upd(sB, mB, laccB, oB, kvt == lastB, qtB, kv0, paB);

      // ---- PV for both q-tiles, shared V fragments ----
      __builtin_amdgcn_s_setprio(1);
      #pragma unroll
      for (int n = 0; n < 4; ++n) {
        int row = n * 16 + l15;
        #pragma unroll
        for (int ks = 0; ks < 4; ++ks) {
          uint4 u = *(const uint4*)&Vt32[row * 66 + ks * 16 + lg * 4];
          short8 vf = __builtin_bit_cast(short8, u);
          oA[n] = __builtin_amdgcn_mfma_f32_16x16x32_bf16(paA[ks], vf, oA[n], 0, 0, 0);
          if (bAct)
            oB[n] = __builtin_amdgcn_mfma_f32_16x16x32_bf16(paB[ks], vf, oB[n], 0, 0, 0);
        }
      }
      __builtin_amdgcn_s_setprio(0);

      cv0 = nv0; cv1 = nv1; cv2 = nv2; cv3 = nv3;
    }
  }

  // write normalized outputs for both q-tiles (inv redistributed from q=l15 lanes)
  float invA = 1.f / laccA;
  float invB = 1.f / laccB;
  #pragma unroll
  for (int r = 0; r < 4; ++r) {
    float ivA = __shfl(invA, lg * 4 + r, 64);
    unsigned short* opA = AO + hbaseO + (size_t)(qtA * 64 + qrowbase + r) * D_MODEL;
    #pragma unroll
    for (int n = 0; n < 4; ++n) opA[n * 16 + l15] = f2bf(oA[n][r] * ivA);
    float ivB = __shfl(invB, lg * 4 + r, 64);
    unsigned short* opB = AO + hbaseO + (size_t)(qtB * 64 + qrowbase + r) * D_MODEL;
    #pragma unroll
    for (int n = 0; n < 4; ++n) opB[n * 16 + l15] = f2bf(oB[n][r] * ivB);
  }
}

extern "C" void kernel_launch(void* const* d_in, const int* in_sizes, int n_in,
                              void* d_out, int out_size, void* d_ws, size_t ws_size,
                              hipStream_t stream) {
  const float* x   = (const float*)d_in[0];
  const float* WQw = (const float*)d_in[1];
  const float* WQb = (const float*)d_in[2];
  const float* WKw = (const float*)d_in[3];
  const float* WKb = (const float*)d_in[4];
  const float* WVw = (const float*)d_in[5];
  const float* WVb = (const float*)d_in[6];
  const float* WOw = (const float*)d_in[7];
  const float* WOb = (const float*)d_in[8];
  float* out = (float*)d_out;

  const int M = BATCH * SEQ;       // 8192
  const int D = D_MODEL;           // 1024
  const int NX = M * D;            // 8388608
  const int NW = D * D;            // 1048576

  unsigned short* xb = (unsigned short*)d_ws;
  unsigned short* wq = xb + NX;        // wq|wk|wv|wo contiguous (cvt4)
  unsigned short* wo = wq + 3 * NW;
  unsigned short* QKVb = wq + 4 * NW;  // [8192][3072]
  unsigned short* AOb = xb;            // reuse x-bf16 region after QKV projection

  cvt_kernel<<<NX / 8 / 256, 256, 0, stream>>>(x, xb, NX);
  cvt4_kernel<<<dim3(NW / 8 / 256, 4), 256, 0, stream>>>(WQw, WKw, WVw, WOw, wq, NW);

  const float qscale = 0.125f * 1.4426950408889634f;  // softmax scale + log2(e) folded into Q
  // fused QKV projection: [8192,1024] x [3072,1024]^T -> [8192,3072]
  gemm_bt<unsigned short><<<dim3(3 * D / 128, M / 128), 256, 0, stream>>>(
      xb, wq, WQb, WKb, WVb, QKVb, M, 3 * D, D, 1024, qscale);

  attn_kernel<<<1024, 256, 0, stream>>>(QKVb, AOb);

  gemm_bt<float><<<dim3(D / 128, M / 128), 256, 0, stream>>>(
      AOb, wo, WOb, WOb, WOb, out, M, D, D, 0, 1.0f);
}

// Round 10
// 213.380 us; speedup vs baseline: 1.0862x; 1.0862x over previous
//
#include <hip/hip_runtime.h>
#include <hip/hip_bf16.h>
#include <stdint.h>

#define D_MODEL 1024
#define NHEAD 16
#define SEQ 2048
#define BATCH 4
#define DK 64
#define QKVSTR 3072

typedef __attribute__((ext_vector_type(8))) short short8;
typedef __attribute__((ext_vector_type(4))) float f32x4;

#if __has_builtin(__builtin_amdgcn_exp2f)
#define EXP2(x) __builtin_amdgcn_exp2f(x)
#else
#define EXP2(x) exp2f(x)
#endif

__device__ inline unsigned short f2bf(float f) {
  unsigned int u = __builtin_bit_cast(unsigned int, f);
  unsigned int r = (u + 0x7fffu + ((u >> 16) & 1u)) >> 16;
  return (unsigned short)r;
}

#define GLOAD_LDS16(g, l) \
  __builtin_amdgcn_global_load_lds((const __attribute__((address_space(1))) unsigned int*)(g), \
      (__attribute__((address_space(3))) unsigned int*)(l), 16, 0, 0)

// ---------------- f32 -> bf16 convert ----------------
__global__ void cvt_kernel(const float* __restrict__ in, unsigned short* __restrict__ out, int n) {
  int i = (blockIdx.x * 256 + threadIdx.x) * 8;
  if (i >= n) return;
  const float4* p = (const float4*)(in + i);
  float4 a = p[0], b = p[1];
  union { unsigned short u[8]; uint4 v; } r;
  r.u[0] = f2bf(a.x); r.u[1] = f2bf(a.y); r.u[2] = f2bf(a.z); r.u[3] = f2bf(a.w);
  r.u[4] = f2bf(b.x); r.u[5] = f2bf(b.y); r.u[6] = f2bf(b.z); r.u[7] = f2bf(b.w);
  *(uint4*)(out + i) = r.v;
}

// 4 weight matrices in one dispatch; outputs contiguous at out + by*n
__global__ void cvt4_kernel(const float* __restrict__ i0, const float* __restrict__ i1,
                            const float* __restrict__ i2, const float* __restrict__ i3,
                            unsigned short* __restrict__ out, int n) {
  const int by = blockIdx.y;
  const float* in = (by == 0) ? i0 : (by == 1) ? i1 : (by == 2) ? i2 : i3;
  unsigned short* o = out + (size_t)by * n;
  int i = (blockIdx.x * 256 + threadIdx.x) * 8;
  if (i >= n) return;
  const float4* p = (const float4*)(in + i);
  float4 a = p[0], b = p[1];
  union { unsigned short u[8]; uint4 v; } r;
  r.u[0] = f2bf(a.x); r.u[1] = f2bf(a.y); r.u[2] = f2bf(a.z); r.u[3] = f2bf(a.w);
  r.u[4] = f2bf(b.x); r.u[5] = f2bf(b.y); r.u[6] = f2bf(b.z); r.u[7] = f2bf(b.w);
  *(uint4*)(o + i) = r.v;
}

// ---------------- GEMM: C[M,N] = f(A[M,K] * B[N,K]^T + bias) ----------------
// bias selected per 1024-column section from b0/b1/b2; cols < qcols scaled by alphaQ.
template <typename CT>
__global__ __launch_bounds__(256)
void gemm_bt(const unsigned short* __restrict__ A, const unsigned short* __restrict__ B,
             const float* __restrict__ b0, const float* __restrict__ b1,
             const float* __restrict__ b2, CT* __restrict__ C, int M, int N, int K,
             int qcols, float alphaQ) {
  __shared__ unsigned short As[128 * 64];
  __shared__ unsigned short Bs[128 * 64];
  const int t = threadIdx.x;
  const int l = t & 63;
  const int w = t >> 6;
  const int wr = w >> 1, wc = w & 1;
  const int l15 = l & 15, lg = l >> 4;
  const int m0 = blockIdx.y * 128, n0 = blockIdx.x * 128;

  f32x4 acc[4][4] = {};

  const int srow = t >> 3;       // 0..31
  const int scol = (t & 7) * 8;  // 0..56

  for (int k0 = 0; k0 < K; k0 += 64) {
    #pragma unroll
    for (int i = 0; i < 4; ++i) {
      GLOAD_LDS16(A + (size_t)(m0 + i * 32 + srow) * K + k0 + scol, &As[(i * 32 + srow) * 64 + scol]);
      GLOAD_LDS16(B + (size_t)(n0 + i * 32 + srow) * K + k0 + scol, &Bs[(i * 32 + srow) * 64 + scol]);
    }
    __syncthreads();
    #pragma unroll
    for (int kk = 0; kk < 2; ++kk) {
      short8 af[4], bfr[4];
      #pragma unroll
      for (int m = 0; m < 4; ++m)
        af[m] = *(const short8*)&As[(wr * 64 + m * 16 + l15) * 64 + kk * 32 + lg * 8];
      #pragma unroll
      for (int n = 0; n < 4; ++n)
        bfr[n] = *(const short8*)&Bs[(wc * 64 + n * 16 + l15) * 64 + kk * 32 + lg * 8];
      #pragma unroll
      for (int m = 0; m < 4; ++m)
        #pragma unroll
        for (int n = 0; n < 4; ++n)
          acc[m][n] = __builtin_amdgcn_mfma_f32_16x16x32_bf16(af[m], bfr[n], acc[m][n], 0, 0, 0);
    }
    __syncthreads();
  }

  #pragma unroll
  for (int m = 0; m < 4; ++m) {
    #pragma unroll
    for (int n = 0; n < 4; ++n) {
      int col = n0 + wc * 64 + n * 16 + l15;
      const float* bp = (col < 1024) ? b0 : (col < 2048) ? b1 : b2;
      float bz = bp[col & 1023];
      #pragma unroll
      for (int r = 0; r < 4; ++r) {
        int row = m0 + wr * 64 + m * 16 + lg * 4 + r;
        float v = acc[m][n][r] + bz;
        if (col < qcols) v *= alphaQ;
        if constexpr (sizeof(CT) == 2) {
          C[(size_t)row * N + col] = (CT)f2bf(v);
        } else {
          C[(size_t)row * N + col] = v;
        }
      }
    }
  }
}

// ---------------- causal flash attention: paired q-tiles, swapped QK^T, register-P ----------------
// QKV: [B*S, 3072] bf16 rows = [Q | K | V], head h at col h*64 within each section.
// Q pre-scaled by 0.125*log2(e); softmax in exp2 domain.
// S^T via mfma(K,Q): lane owns q=l15; kv = n*16 + lg*4 + r.
// P never touches LDS: PV's kv axis is permuted (applied to BOTH P and V) so each lane's
// owned P values ARE its A-fragment: pa[ks] = bf16(s[2ks], s[2ks+1]).
// V staging writes to permuted positions: pos = (p&17) | ((p&6)<<1) | ((p&8)>>2).
// Pipeline: K(t+1) DMA (dbuf Ks) + V(t+1) reg loads in flight across barrier2 (lgkm-only).
__global__ __launch_bounds__(256, 3)
void attn_kernel(const unsigned short* __restrict__ QKV, unsigned short* __restrict__ AO) {
  __shared__ unsigned short Ks[2][64 * 64];
  __shared__ unsigned int Vt32[64 * 36];       // [d][kv-pair slot] packed 2xbf16 per dword

  const int t = threadIdx.x;
  const int l = t & 63;
  const int w = t >> 6;
  const int l15 = l & 15, lg = l >> 4;
  const int id = blockIdx.x;
  const int i = id >> 6;        // 0..15
  const int bh = id & 63;       // same-head blocks differ by 64 -> same XCD
  const int qtA = 31 - i;       // long q-tile
  const int qtB = i;            // short q-tile
  const int b = bh >> 4, h = bh & 15;
  const size_t hbase = (size_t)b * SEQ * QKVSTR + h * DK;
  const size_t hbaseO = (size_t)b * SEQ * D_MODEL + h * DK;

  // hoisted Q fragments for both q-tiles (MFMA B-operand)
  short8 qfA[2], qfB[2];
  {
    const unsigned short* qp = QKV + hbase + (size_t)(qtA * 64 + w * 16 + l15) * QKVSTR + lg * 8;
    qfA[0] = *(const short8*)qp; qfA[1] = *(const short8*)(qp + 32);
    qp = QKV + hbase + (size_t)(qtB * 64 + w * 16 + l15) * QKVSTR + lg * 8;
    qfB[0] = *(const short8*)qp; qfB[1] = *(const short8*)(qp + 32);
  }

  f32x4 oA[4] = {}, oB[4] = {};
  float laccA = 0.f, laccB = 0.f;
  float mA = -INFINITY, mB = -INFINITY;

  // K staging map: thread t covers row srow(+32), 16B chunk sc8; source chunk XOR-swizzled
  const int srow = t >> 3, sc8 = t & 7;
  const int kssw = sc8 ^ (srow & 7);
  // V staging map: thread covers kv-pair vp_, 8 d values; dest slot permuted for register-P PV
  const int vp_ = t & 31;                 // kv-pair index 0..31
  const int vdh = (t >> 5) * 8;           // d offset 0..56
  const int vpos = (vp_ & 17) | ((vp_ & 6) << 1) | ((vp_ & 8) >> 2);  // permuted slot
  const int qrowbase = w * 16 + lg * 4;   // o rows: qt*64 + qrowbase + r

  auto issueK = [&](int kvt, int buf) {
    const unsigned short* kp = QKV + hbase + 1024 + (size_t)(kvt * 64 + srow) * QKVSTR + kssw * 8;
    GLOAD_LDS16(kp, &Ks[buf][srow * 64 + sc8 * 8]);
    GLOAD_LDS16(kp + (size_t)32 * QKVSTR, &Ks[buf][(32 + srow) * 64 + sc8 * 8]);
  };

  // softmax update (S^T layout): q=l15 scalar stats; P packed in-register into pa
  auto softmax_upd = [&](f32x4 (&s)[4], float& m, float& lacc, f32x4 (&o)[4],
                         bool diag, int qt, int kv0, short8 (&pa)[2]) {
    const int q = qt * 64 + w * 16 + l15;
    if (diag) {
      #pragma unroll
      for (int n = 0; n < 4; ++n)
        #pragma unroll
        for (int r = 0; r < 4; ++r)
          if (kv0 + n * 16 + lg * 4 + r > q) s[n][r] = -INFINITY;
    }
    float pm = -INFINITY;
    #pragma unroll
    for (int n = 0; n < 4; ++n)
      #pragma unroll
      for (int r = 0; r < 4; ++r) pm = fmaxf(pm, s[n][r]);
    pm = fmaxf(pm, __shfl_xor(pm, 16, 64));
    pm = fmaxf(pm, __shfl_xor(pm, 32, 64));
    float mx = fmaxf(m, pm);
    if (!__all(mx - m <= 11.0f)) {       // defer-max: rescale only on real growth
      float al = EXP2(m - mx);
      m = mx;
      lacc *= al;
      float alo[4];
      #pragma unroll
      for (int r = 0; r < 4; ++r) alo[r] = __shfl(al, lg * 4 + r, 64);
      #pragma unroll
      for (int n = 0; n < 4; ++n)
        #pragma unroll
        for (int r = 0; r < 4; ++r) o[n][r] *= alo[r];
    }
    float ps = 0.f;
    unsigned int pw[8];
    #pragma unroll
    for (int n = 0; n < 4; ++n) {
      float p0 = EXP2(s[n][0] - m), p1 = EXP2(s[n][1] - m);
      float p2 = EXP2(s[n][2] - m), p3 = EXP2(s[n][3] - m);
      ps += (p0 + p1) + (p2 + p3);
      pw[n * 2]     = (unsigned int)f2bf(p0) | ((unsigned int)f2bf(p1) << 16);
      pw[n * 2 + 1] = (unsigned int)f2bf(p2) | ((unsigned int)f2bf(p3) << 16);
    }
    ps += __shfl_xor(ps, 16, 64);
    ps += __shfl_xor(ps, 32, 64);
    lacc += ps;
    uint4 u0 = make_uint4(pw[0], pw[1], pw[2], pw[3]);
    uint4 u1 = make_uint4(pw[4], pw[5], pw[6], pw[7]);
    pa[0] = __builtin_bit_cast(short8, u0);
    pa[1] = __builtin_bit_cast(short8, u1);
  };

  const int ntiles = qtA + 1;

  // prologue: tile 0 staged
  short8 cv0, cv1;
  issueK(0, 0);
  {
    const unsigned short* vp = QKV + hbase + 2048 + (size_t)(2 * vp_) * QKVSTR + vdh;
    cv0 = *(const short8*)vp;
    cv1 = *(const short8*)(vp + QKVSTR);
  }

  int p = 0;
  for (int kvt = 0; kvt < ntiles; ++kvt) {
    const int kv0 = kvt * 64;
    // barrier1: my K(t) DMA + V(t) regs arrived; all waves done with Vt(t-1) reads
    asm volatile("s_waitcnt vmcnt(0)" ::: "memory");
    __builtin_amdgcn_s_barrier();
    __builtin_amdgcn_sched_barrier(0);

    // stage V(t) to LDS (packed transpose, permuted slot), then prefetch tile t+1
    #pragma unroll
    for (int j = 0; j < 8; ++j) {
      unsigned int dw = (unsigned int)(unsigned short)cv0[j] |
                        ((unsigned int)(unsigned short)cv1[j] << 16);
      Vt32[(vdh + j) * 36 + vpos] = dw;
    }
    short8 nv0 = cv0, nv1 = cv1;
    if (kvt + 1 < ntiles) {
      issueK(kvt + 1, p ^ 1);
      const unsigned short* vp = QKV + hbase + 2048 + (size_t)(kv0 + 64 + 2 * vp_) * QKVSTR + vdh;
      nv0 = *(const short8*)vp;
      nv1 = *(const short8*)(vp + QKVSTR);
    }
    // barrier2: V writes visible; prefetch loads stay in flight (no vmcnt drain)
    asm volatile("s_waitcnt lgkmcnt(0)" ::: "memory");
    __builtin_amdgcn_s_barrier();
    __builtin_amdgcn_sched_barrier(0);

    const bool bAct = (kvt <= qtB);
    short8 paA[2], paB[2];
    f32x4 sA[4], sB[4];

    // ---- merged swapped QK^T: each K fragment read once, used for both q-tiles ----
    __builtin_amdgcn_s_setprio(1);
    #pragma unroll
    for (int n = 0; n < 4; ++n) {
      int row = n * 16 + l15;
      short8 kf0 = *(const short8*)&Ks[p][row * 64 + ((lg ^ (row & 7)) * 8)];
      short8 kf1 = *(const short8*)&Ks[p][row * 64 + (((4 + lg) ^ (row & 7)) * 8)];
      f32x4 z = {};
      z = __builtin_amdgcn_mfma_f32_16x16x32_bf16(kf0, qfA[0], z, 0, 0, 0);
      z = __builtin_amdgcn_mfma_f32_16x16x32_bf16(kf1, qfA[1], z, 0, 0, 0);
      sA[n] = z;
      if (bAct) {
        f32x4 y = {};
        y = __builtin_amdgcn_mfma_f32_16x16x32_bf16(kf0, qfB[0], y, 0, 0, 0);
        y = __builtin_amdgcn_mfma_f32_16x16x32_bf16(kf1, qfB[1], y, 0, 0, 0);
        sB[n] = y;
      }
    }
    __builtin_amdgcn_s_setprio(0);

    softmax_upd(sA, mA, laccA, oA, kvt == qtA, qtA, kv0, paA);
    if (bAct) softmax_upd(sB, mB, laccB, oB, kvt == qtB, qtB, kv0, paB);

    // ---- PV for both q-tiles, shared V fragments (kv-permuted consistently with pa) ----
    __builtin_amdgcn_s_setprio(1);
    #pragma unroll
    for (int n = 0; n < 4; ++n) {
      int row = n * 16 + l15;
      uint4 u0 = *(const uint4*)&Vt32[row * 36 + lg * 4];
      uint4 u1 = *(const uint4*)&Vt32[row * 36 + 16 + lg * 4];
      short8 vf0 = __builtin_bit_cast(short8, u0);
      short8 vf1 = __builtin_bit_cast(short8, u1);
      oA[n] = __builtin_amdgcn_mfma_f32_16x16x32_bf16(paA[0], vf0, oA[n], 0, 0, 0);
      oA[n] = __builtin_amdgcn_mfma_f32_16x16x32_bf16(paA[1], vf1, oA[n], 0, 0, 0);
      if (bAct) {
        oB[n] = __builtin_amdgcn_mfma_f32_16x16x32_bf16(paB[0], vf0, oB[n], 0, 0, 0);
        oB[n] = __builtin_amdgcn_mfma_f32_16x16x32_bf16(paB[1], vf1, oB[n], 0, 0, 0);
      }
    }
    __builtin_amdgcn_s_setprio(0);

    cv0 = nv0; cv1 = nv1;
    p ^= 1;
  }

  // write normalized outputs for both q-tiles (inv redistributed from q=l15 lanes)
  float invA = 1.f / laccA;
  float invB = 1.f / laccB;
  #pragma unroll
  for (int r = 0; r < 4; ++r) {
    float ivA = __shfl(invA, lg * 4 + r, 64);
    unsigned short* opA = AO + hbaseO + (size_t)(qtA * 64 + qrowbase + r) * D_MODEL;
    #pragma unroll
    for (int n = 0; n < 4; ++n) opA[n * 16 + l15] = f2bf(oA[n][r] * ivA);
    float ivB = __shfl(invB, lg * 4 + r, 64);
    unsigned short* opB = AO + hbaseO + (size_t)(qtB * 64 + qrowbase + r) * D_MODEL;
    #pragma unroll
    for (int n = 0; n < 4; ++n) opB[n * 16 + l15] = f2bf(oB[n][r] * ivB);
  }
}

extern "C" void kernel_launch(void* const* d_in, const int* in_sizes, int n_in,
                              void* d_out, int out_size, void* d_ws, size_t ws_size,
                              hipStream_t stream) {
  const float* x   = (const float*)d_in[0];
  const float* WQw = (const float*)d_in[1];
  const float* WQb = (const float*)d_in[2];
  const float* WKw = (const float*)d_in[3];
  const float* WKb = (const float*)d_in[4];
  const float* WVw = (const float*)d_in[5];
  const float* WVb = (const float*)d_in[6];
  const float* WOw = (const float*)d_in[7];
  const float* WOb = (const float*)d_in[8];
  float* out = (float*)d_out;

  const int M = BATCH * SEQ;       // 8192
  const int D = D_MODEL;           // 1024
  const int NX = M * D;            // 8388608
  const int NW = D * D;            // 1048576

  unsigned short* xb = (unsigned short*)d_ws;
  unsigned short* wq = xb + NX;        // wq|wk|wv|wo contiguous (cvt4)
  unsigned short* wo = wq + 3 * NW;
  unsigned short* QKVb = wq + 4 * NW;  // [8192][3072]
  unsigned short* AOb = xb;            // reuse x-bf16 region after QKV projection

  cvt_kernel<<<NX / 8 / 256, 256, 0, stream>>>(x, xb, NX);
  cvt4_kernel<<<dim3(NW / 8 / 256, 4), 256, 0, stream>>>(WQw, WKw, WVw, WOw, wq, NW);

  const float qscale = 0.125f * 1.4426950408889634f;  // softmax scale + log2(e) folded into Q
  // fused QKV projection: [8192,1024] x [3072,1024]^T -> [8192,3072]
  gemm_bt<unsigned short><<<dim3(3 * D / 128, M / 128), 256, 0, stream>>>(
      xb, wq, WQb, WKb, WVb, QKVb, M, 3 * D, D, 1024, qscale);

  attn_kernel<<<1024, 256, 0, stream>>>(QKVb, AOb);

  gemm_bt<float><<<dim3(D / 128, M / 128), 256, 0, stream>>>(
      AOb, wo, WOb, WOb, WOb, out, M, D, D, 0, 1.0f);
}

// Round 11
// 186.947 us; speedup vs baseline: 1.2397x; 1.1414x over previous
//
#include <hip/hip_runtime.h>
#include <hip/hip_bf16.h>
#include <stdint.h>

#define D_MODEL 1024
#define NHEAD 16
#define SEQ 2048
#define BATCH 4
#define DK 64
#define QKVSTR 3072

typedef __attribute__((ext_vector_type(8))) short short8;
typedef __attribute__((ext_vector_type(4))) float f32x4;

#if __has_builtin(__builtin_amdgcn_exp2f)
#define EXP2(x) __builtin_amdgcn_exp2f(x)
#else
#define EXP2(x) exp2f(x)
#endif

__device__ inline unsigned short f2bf(float f) {
  unsigned int u = __builtin_bit_cast(unsigned int, f);
  unsigned int r = (u + 0x7fffu + ((u >> 16) & 1u)) >> 16;
  return (unsigned short)r;
}

__device__ inline unsigned int cvt_pk_bf16(float lo, float hi) {
  unsigned int d;
  asm("v_cvt_pk_bf16_f32 %0, %1, %2" : "=v"(d) : "v"(lo), "v"(hi));
  return d;
}

#define GLOAD_LDS16(g, l) \
  __builtin_amdgcn_global_load_lds((const __attribute__((address_space(1))) unsigned int*)(g), \
      (__attribute__((address_space(3))) unsigned int*)(l), 16, 0, 0)

// ---------------- f32 -> bf16 convert ----------------
__global__ void cvt_kernel(const float* __restrict__ in, unsigned short* __restrict__ out, int n) {
  int i = (blockIdx.x * 256 + threadIdx.x) * 8;
  if (i >= n) return;
  const float4* p = (const float4*)(in + i);
  float4 a = p[0], b = p[1];
  union { unsigned short u[8]; uint4 v; } r;
  r.u[0] = f2bf(a.x); r.u[1] = f2bf(a.y); r.u[2] = f2bf(a.z); r.u[3] = f2bf(a.w);
  r.u[4] = f2bf(b.x); r.u[5] = f2bf(b.y); r.u[6] = f2bf(b.z); r.u[7] = f2bf(b.w);
  *(uint4*)(out + i) = r.v;
}

// 4 weight matrices in one dispatch; outputs contiguous at out + by*n
__global__ void cvt4_kernel(const float* __restrict__ i0, const float* __restrict__ i1,
                            const float* __restrict__ i2, const float* __restrict__ i3,
                            unsigned short* __restrict__ out, int n) {
  const int by = blockIdx.y;
  const float* in = (by == 0) ? i0 : (by == 1) ? i1 : (by == 2) ? i2 : i3;
  unsigned short* o = out + (size_t)by * n;
  int i = (blockIdx.x * 256 + threadIdx.x) * 8;
  if (i >= n) return;
  const float4* p = (const float4*)(in + i);
  float4 a = p[0], b = p[1];
  union { unsigned short u[8]; uint4 v; } r;
  r.u[0] = f2bf(a.x); r.u[1] = f2bf(a.y); r.u[2] = f2bf(a.z); r.u[3] = f2bf(a.w);
  r.u[4] = f2bf(b.x); r.u[5] = f2bf(b.y); r.u[6] = f2bf(b.z); r.u[7] = f2bf(b.w);
  *(uint4*)(o + i) = r.v;
}

// ---------------- GEMM: C[M,N] = f(A[M,K] * B[N,K]^T + bias) ----------------
// bias selected per 1024-column section from b0/b1/b2; cols < qcols scaled by alphaQ.
template <typename CT>
__global__ __launch_bounds__(256)
void gemm_bt(const unsigned short* __restrict__ A, const unsigned short* __restrict__ B,
             const float* __restrict__ b0, const float* __restrict__ b1,
             const float* __restrict__ b2, CT* __restrict__ C, int M, int N, int K,
             int qcols, float alphaQ) {
  __shared__ unsigned short As[128 * 64];
  __shared__ unsigned short Bs[128 * 64];
  const int t = threadIdx.x;
  const int l = t & 63;
  const int w = t >> 6;
  const int wr = w >> 1, wc = w & 1;
  const int l15 = l & 15, lg = l >> 4;
  const int m0 = blockIdx.y * 128, n0 = blockIdx.x * 128;

  f32x4 acc[4][4] = {};

  const int srow = t >> 3;       // 0..31
  const int scol = (t & 7) * 8;  // 0..56

  for (int k0 = 0; k0 < K; k0 += 64) {
    #pragma unroll
    for (int i = 0; i < 4; ++i) {
      GLOAD_LDS16(A + (size_t)(m0 + i * 32 + srow) * K + k0 + scol, &As[(i * 32 + srow) * 64 + scol]);
      GLOAD_LDS16(B + (size_t)(n0 + i * 32 + srow) * K + k0 + scol, &Bs[(i * 32 + srow) * 64 + scol]);
    }
    __syncthreads();
    #pragma unroll
    for (int kk = 0; kk < 2; ++kk) {
      short8 af[4], bfr[4];
      #pragma unroll
      for (int m = 0; m < 4; ++m)
        af[m] = *(const short8*)&As[(wr * 64 + m * 16 + l15) * 64 + kk * 32 + lg * 8];
      #pragma unroll
      for (int n = 0; n < 4; ++n)
        bfr[n] = *(const short8*)&Bs[(wc * 64 + n * 16 + l15) * 64 + kk * 32 + lg * 8];
      #pragma unroll
      for (int m = 0; m < 4; ++m)
        #pragma unroll
        for (int n = 0; n < 4; ++n)
          acc[m][n] = __builtin_amdgcn_mfma_f32_16x16x32_bf16(af[m], bfr[n], acc[m][n], 0, 0, 0);
    }
    __syncthreads();
  }

  #pragma unroll
  for (int m = 0; m < 4; ++m) {
    #pragma unroll
    for (int n = 0; n < 4; ++n) {
      int col = n0 + wc * 64 + n * 16 + l15;
      const float* bp = (col < 1024) ? b0 : (col < 2048) ? b1 : b2;
      float bz = bp[col & 1023];
      #pragma unroll
      for (int r = 0; r < 4; ++r) {
        int row = m0 + wr * 64 + m * 16 + lg * 4 + r;
        float v = acc[m][n][r] + bz;
        if (col < qcols) v *= alphaQ;
        if constexpr (sizeof(CT) == 2) {
          C[(size_t)row * N + col] = (CT)f2bf(v);
        } else {
          C[(size_t)row * N + col] = v;
        }
      }
    }
  }
}

// ---------------- causal flash attention: unpaired, swapped QK^T, register-P ----------------
// QKV: [B*S, 3072] bf16 rows = [Q | K | V], head h at col h*64 within each section.
// Q pre-scaled by 0.125*log2(e); softmax in exp2 domain.
// One q-tile per block (2048 blocks, heavy tiles dispatched first) for 6+ blocks/CU.
// S^T via mfma(K,Q): lane owns q=l15; kv = n*16 + lg*4 + r.
// P never touches LDS (kv-permutation absorbed into V staging slot).
// Pipeline: K(t+1) DMA (dbuf Ks) + V(t+1) reg loads in flight across barrier2 (lgkm-only).
__global__ __launch_bounds__(256, 3)
void attn_kernel(const unsigned short* __restrict__ QKV, unsigned short* __restrict__ AO) {
  __shared__ unsigned short Ks[2][64 * 64];
  __shared__ unsigned int Vt32[64 * 36];       // [d][kv-pair slot] packed 2xbf16 per dword

  const int t = threadIdx.x;
  const int l = t & 63;
  const int w = t >> 6;
  const int l15 = l & 15, lg = l >> 4;
  const int id = blockIdx.x;
  const int qt = 31 - (id >> 6);  // heaviest q-tiles dispatched first
  const int bh = id & 63;         // same-head blocks differ by 64 -> same XCD
  const int b = bh >> 4, h = bh & 15;
  const size_t hbase = (size_t)b * SEQ * QKVSTR + h * DK;
  const size_t hbaseO = (size_t)b * SEQ * D_MODEL + h * DK;

  // hoisted Q fragments (MFMA B-operand)
  short8 qf[2];
  {
    const unsigned short* qp = QKV + hbase + (size_t)(qt * 64 + w * 16 + l15) * QKVSTR + lg * 8;
    qf[0] = *(const short8*)qp; qf[1] = *(const short8*)(qp + 32);
  }

  f32x4 o[4] = {};
  float lacc = 0.f;
  float m = -INFINITY;

  // K staging map: thread t covers row srow(+32), 16B chunk sc8; source chunk XOR-swizzled
  const int srow = t >> 3, sc8 = t & 7;
  const int kssw = sc8 ^ (srow & 7);
  // V staging map: thread covers kv-pair vp_, 8 d values; dest slot permuted for register-P PV
  const int vp_ = t & 31;                 // kv-pair index 0..31
  const int vdh = (t >> 5) * 8;           // d offset 0..56
  const int vpos = (vp_ & 17) | ((vp_ & 6) << 1) | ((vp_ & 8) >> 2);  // permuted slot
  const int qrowbase = w * 16 + lg * 4;   // o rows: qt*64 + qrowbase + r

  auto issueK = [&](int kvt, int buf) {
    const unsigned short* kp = QKV + hbase + 1024 + (size_t)(kvt * 64 + srow) * QKVSTR + kssw * 8;
    GLOAD_LDS16(kp, &Ks[buf][srow * 64 + sc8 * 8]);
    GLOAD_LDS16(kp + (size_t)32 * QKVSTR, &Ks[buf][(32 + srow) * 64 + sc8 * 8]);
  };

  const int ntiles = qt + 1;

  // prologue: tile 0 staged
  short8 cv0, cv1;
  issueK(0, 0);
  {
    const unsigned short* vp = QKV + hbase + 2048 + (size_t)(2 * vp_) * QKVSTR + vdh;
    cv0 = *(const short8*)vp;
    cv1 = *(const short8*)(vp + QKVSTR);
  }

  int p = 0;
  for (int kvt = 0; kvt < ntiles; ++kvt) {
    const int kv0 = kvt * 64;
    // barrier1: my K(t) DMA + V(t) regs arrived; all waves done with Vt(t-1) reads
    asm volatile("s_waitcnt vmcnt(0)" ::: "memory");
    __builtin_amdgcn_s_barrier();
    __builtin_amdgcn_sched_barrier(0);

    // stage V(t) to LDS (packed transpose, permuted slot), then prefetch tile t+1
    #pragma unroll
    for (int j = 0; j < 8; ++j) {
      unsigned int dw = (unsigned int)(unsigned short)cv0[j] |
                        ((unsigned int)(unsigned short)cv1[j] << 16);
      Vt32[(vdh + j) * 36 + vpos] = dw;
    }
    short8 nv0 = cv0, nv1 = cv1;
    if (kvt + 1 < ntiles) {
      issueK(kvt + 1, p ^ 1);
      const unsigned short* vp = QKV + hbase + 2048 + (size_t)(kv0 + 64 + 2 * vp_) * QKVSTR + vdh;
      nv0 = *(const short8*)vp;
      nv1 = *(const short8*)(vp + QKVSTR);
    }
    // barrier2: V writes visible; prefetch loads stay in flight (no vmcnt drain)
    asm volatile("s_waitcnt lgkmcnt(0)" ::: "memory");
    __builtin_amdgcn_s_barrier();
    __builtin_amdgcn_sched_barrier(0);

    f32x4 s[4];
    // ---- swapped QK^T ----
    __builtin_amdgcn_s_setprio(1);
    #pragma unroll
    for (int n = 0; n < 4; ++n) {
      int row = n * 16 + l15;
      short8 kf0 = *(const short8*)&Ks[p][row * 64 + ((lg ^ (row & 7)) * 8)];
      short8 kf1 = *(const short8*)&Ks[p][row * 64 + (((4 + lg) ^ (row & 7)) * 8)];
      f32x4 z = {};
      z = __builtin_amdgcn_mfma_f32_16x16x32_bf16(kf0, qf[0], z, 0, 0, 0);
      z = __builtin_amdgcn_mfma_f32_16x16x32_bf16(kf1, qf[1], z, 0, 0, 0);
      s[n] = z;
    }
    __builtin_amdgcn_s_setprio(0);

    // ---- softmax (S^T layout, q=l15 scalar stats), P packed in-register ----
    short8 pa[2];
    {
      const int q = qt * 64 + w * 16 + l15;
      if (kvt == qt) {   // diagonal tile: causal mask
        #pragma unroll
        for (int n = 0; n < 4; ++n)
          #pragma unroll
          for (int r = 0; r < 4; ++r)
            if (kv0 + n * 16 + lg * 4 + r > q) s[n][r] = -INFINITY;
      }
      float pm = -INFINITY;
      #pragma unroll
      for (int n = 0; n < 4; ++n)
        #pragma unroll
        for (int r = 0; r < 4; ++r) pm = fmaxf(pm, s[n][r]);
      pm = fmaxf(pm, __shfl_xor(pm, 16, 64));
      pm = fmaxf(pm, __shfl_xor(pm, 32, 64));
      float mx = fmaxf(m, pm);
      if (!__all(mx - m <= 11.0f)) {     // defer-max: rescale only on real growth
        float al = EXP2(m - mx);
        m = mx;
        lacc *= al;
        float alo[4];
        #pragma unroll
        for (int r = 0; r < 4; ++r) alo[r] = __shfl(al, lg * 4 + r, 64);
        #pragma unroll
        for (int n = 0; n < 4; ++n)
          #pragma unroll
          for (int r = 0; r < 4; ++r) o[n][r] *= alo[r];
      }
      float ps = 0.f;
      unsigned int pw[8];
      #pragma unroll
      for (int n = 0; n < 4; ++n) {
        float p0 = EXP2(s[n][0] - m), p1 = EXP2(s[n][1] - m);
        float p2 = EXP2(s[n][2] - m), p3 = EXP2(s[n][3] - m);
        ps += (p0 + p1) + (p2 + p3);
        pw[n * 2]     = cvt_pk_bf16(p0, p1);
        pw[n * 2 + 1] = cvt_pk_bf16(p2, p3);
      }
      ps += __shfl_xor(ps, 16, 64);
      ps += __shfl_xor(ps, 32, 64);
      lacc += ps;
      uint4 u0 = make_uint4(pw[0], pw[1], pw[2], pw[3]);
      uint4 u1 = make_uint4(pw[4], pw[5], pw[6], pw[7]);
      pa[0] = __builtin_bit_cast(short8, u0);
      pa[1] = __builtin_bit_cast(short8, u1);
    }

    // ---- PV (kv-permuted consistently with pa) ----
    __builtin_amdgcn_s_setprio(1);
    #pragma unroll
    for (int n = 0; n < 4; ++n) {
      int row = n * 16 + l15;
      uint4 u0 = *(const uint4*)&Vt32[row * 36 + lg * 4];
      uint4 u1 = *(const uint4*)&Vt32[row * 36 + 16 + lg * 4];
      o[n] = __builtin_amdgcn_mfma_f32_16x16x32_bf16(pa[0], __builtin_bit_cast(short8, u0), o[n], 0, 0, 0);
      o[n] = __builtin_amdgcn_mfma_f32_16x16x32_bf16(pa[1], __builtin_bit_cast(short8, u1), o[n], 0, 0, 0);
    }
    __builtin_amdgcn_s_setprio(0);

    cv0 = nv0; cv1 = nv1;
    p ^= 1;
  }

  // write normalized output (inv redistributed from q=l15 lanes)
  float inv = 1.f / lacc;
  #pragma unroll
  for (int r = 0; r < 4; ++r) {
    float iv = __shfl(inv, lg * 4 + r, 64);
    unsigned short* op = AO + hbaseO + (size_t)(qt * 64 + qrowbase + r) * D_MODEL;
    #pragma unroll
    for (int n = 0; n < 4; ++n) op[n * 16 + l15] = f2bf(o[n][r] * iv);
  }
}

extern "C" void kernel_launch(void* const* d_in, const int* in_sizes, int n_in,
                              void* d_out, int out_size, void* d_ws, size_t ws_size,
                              hipStream_t stream) {
  const float* x   = (const float*)d_in[0];
  const float* WQw = (const float*)d_in[1];
  const float* WQb = (const float*)d_in[2];
  const float* WKw = (const float*)d_in[3];
  const float* WKb = (const float*)d_in[4];
  const float* WVw = (const float*)d_in[5];
  const float* WVb = (const float*)d_in[6];
  const float* WOw = (const float*)d_in[7];
  const float* WOb = (const float*)d_in[8];
  float* out = (float*)d_out;

  const int M = BATCH * SEQ;       // 8192
  const int D = D_MODEL;           // 1024
  const int NX = M * D;            // 8388608
  const int NW = D * D;            // 1048576

  unsigned short* xb = (unsigned short*)d_ws;
  unsigned short* wq = xb + NX;        // wq|wk|wv|wo contiguous (cvt4)
  unsigned short* wo = wq + 3 * NW;
  unsigned short* QKVb = wq + 4 * NW;  // [8192][3072]
  unsigned short* AOb = xb;            // reuse x-bf16 region after QKV projection

  cvt_kernel<<<NX / 8 / 256, 256, 0, stream>>>(x, xb, NX);
  cvt4_kernel<<<dim3(NW / 8 / 256, 4), 256, 0, stream>>>(WQw, WKw, WVw, WOw, wq, NW);

  const float qscale = 0.125f * 1.4426950408889634f;  // softmax scale + log2(e) folded into Q
  // fused QKV projection: [8192,1024] x [3072,1024]^T -> [8192,3072]
  gemm_bt<unsigned short><<<dim3(3 * D / 128, M / 128), 256, 0, stream>>>(
      xb, wq, WQb, WKb, WVb, QKVb, M, 3 * D, D, 1024, qscale);

  attn_kernel<<<2048, 256, 0, stream>>>(QKVb, AOb);

  gemm_bt<float><<<dim3(D / 128, M / 128), 256, 0, stream>>>(
      AOb, wo, WOb, WOb, WOb, out, M, D, D, 0, 1.0f);
}

// Round 12
// 186.257 us; speedup vs baseline: 1.2443x; 1.0037x over previous
//
#include <hip/hip_runtime.h>
#include <hip/hip_bf16.h>
#include <stdint.h>

#define D_MODEL 1024
#define NHEAD 16
#define SEQ 2048
#define BATCH 4
#define DK 64
#define QKVSTR 3072

typedef __attribute__((ext_vector_type(8))) short short8;
typedef __attribute__((ext_vector_type(4))) float f32x4;

#if __has_builtin(__builtin_amdgcn_exp2f)
#define EXP2(x) __builtin_amdgcn_exp2f(x)
#else
#define EXP2(x) exp2f(x)
#endif

__device__ inline unsigned short f2bf(float f) {
  unsigned int u = __builtin_bit_cast(unsigned int, f);
  unsigned int r = (u + 0x7fffu + ((u >> 16) & 1u)) >> 16;
  return (unsigned short)r;
}

__device__ inline unsigned int cvt_pk_bf16(float lo, float hi) {
  unsigned int d;
  asm("v_cvt_pk_bf16_f32 %0, %1, %2" : "=v"(d) : "v"(lo), "v"(hi));
  return d;
}

#define GLOAD_LDS16(g, l) \
  __builtin_amdgcn_global_load_lds((const __attribute__((address_space(1))) unsigned int*)(g), \
      (__attribute__((address_space(3))) unsigned int*)(l), 16, 0, 0)

// ---------------- f32 -> bf16 convert ----------------
__global__ void cvt_kernel(const float* __restrict__ in, unsigned short* __restrict__ out, int n) {
  int i = (blockIdx.x * 256 + threadIdx.x) * 8;
  if (i >= n) return;
  const float4* p = (const float4*)(in + i);
  float4 a = p[0], b = p[1];
  union { unsigned short u[8]; uint4 v; } r;
  r.u[0] = f2bf(a.x); r.u[1] = f2bf(a.y); r.u[2] = f2bf(a.z); r.u[3] = f2bf(a.w);
  r.u[4] = f2bf(b.x); r.u[5] = f2bf(b.y); r.u[6] = f2bf(b.z); r.u[7] = f2bf(b.w);
  *(uint4*)(out + i) = r.v;
}

// 4 weight matrices in one dispatch; outputs contiguous at out + by*n
__global__ void cvt4_kernel(const float* __restrict__ i0, const float* __restrict__ i1,
                            const float* __restrict__ i2, const float* __restrict__ i3,
                            unsigned short* __restrict__ out, int n) {
  const int by = blockIdx.y;
  const float* in = (by == 0) ? i0 : (by == 1) ? i1 : (by == 2) ? i2 : i3;
  unsigned short* o = out + (size_t)by * n;
  int i = (blockIdx.x * 256 + threadIdx.x) * 8;
  if (i >= n) return;
  const float4* p = (const float4*)(in + i);
  float4 a = p[0], b = p[1];
  union { unsigned short u[8]; uint4 v; } r;
  r.u[0] = f2bf(a.x); r.u[1] = f2bf(a.y); r.u[2] = f2bf(a.z); r.u[3] = f2bf(a.w);
  r.u[4] = f2bf(b.x); r.u[5] = f2bf(b.y); r.u[6] = f2bf(b.z); r.u[7] = f2bf(b.w);
  *(uint4*)(o + i) = r.v;
}

// ---------------- GEMM: C[M,N] = f(A[M,K] * B[N,K]^T + bias) ----------------
// bias selected per 1024-column section from b0/b1/b2; cols < qcols scaled by alphaQ.
template <typename CT>
__global__ __launch_bounds__(256)
void gemm_bt(const unsigned short* __restrict__ A, const unsigned short* __restrict__ B,
             const float* __restrict__ b0, const float* __restrict__ b1,
             const float* __restrict__ b2, CT* __restrict__ C, int M, int N, int K,
             int qcols, float alphaQ) {
  __shared__ unsigned short As[128 * 64];
  __shared__ unsigned short Bs[128 * 64];
  const int t = threadIdx.x;
  const int l = t & 63;
  const int w = t >> 6;
  const int wr = w >> 1, wc = w & 1;
  const int l15 = l & 15, lg = l >> 4;
  const int m0 = blockIdx.y * 128, n0 = blockIdx.x * 128;

  f32x4 acc[4][4] = {};

  const int srow = t >> 3;       // 0..31
  const int scol = (t & 7) * 8;  // 0..56

  for (int k0 = 0; k0 < K; k0 += 64) {
    #pragma unroll
    for (int i = 0; i < 4; ++i) {
      GLOAD_LDS16(A + (size_t)(m0 + i * 32 + srow) * K + k0 + scol, &As[(i * 32 + srow) * 64 + scol]);
      GLOAD_LDS16(B + (size_t)(n0 + i * 32 + srow) * K + k0 + scol, &Bs[(i * 32 + srow) * 64 + scol]);
    }
    __syncthreads();
    #pragma unroll
    for (int kk = 0; kk < 2; ++kk) {
      short8 af[4], bfr[4];
      #pragma unroll
      for (int m = 0; m < 4; ++m)
        af[m] = *(const short8*)&As[(wr * 64 + m * 16 + l15) * 64 + kk * 32 + lg * 8];
      #pragma unroll
      for (int n = 0; n < 4; ++n)
        bfr[n] = *(const short8*)&Bs[(wc * 64 + n * 16 + l15) * 64 + kk * 32 + lg * 8];
      #pragma unroll
      for (int m = 0; m < 4; ++m)
        #pragma unroll
        for (int n = 0; n < 4; ++n)
          acc[m][n] = __builtin_amdgcn_mfma_f32_16x16x32_bf16(af[m], bfr[n], acc[m][n], 0, 0, 0);
    }
    __syncthreads();
  }

  #pragma unroll
  for (int m = 0; m < 4; ++m) {
    #pragma unroll
    for (int n = 0; n < 4; ++n) {
      int col = n0 + wc * 64 + n * 16 + l15;
      const float* bp = (col < 1024) ? b0 : (col < 2048) ? b1 : b2;
      float bz = bp[col & 1023];
      #pragma unroll
      for (int r = 0; r < 4; ++r) {
        int row = m0 + wr * 64 + m * 16 + lg * 4 + r;
        float v = acc[m][n][r] + bz;
        if (col < qcols) v *= alphaQ;
        if constexpr (sizeof(CT) == 2) {
          C[(size_t)row * N + col] = (CT)f2bf(v);
        } else {
          C[(size_t)row * N + col] = v;
        }
      }
    }
  }
}

// ---------------- causal flash attention: unpaired, swapped QK^T, register-P ----------------
// QKV: [B*S, 3072] bf16 rows = [Q | K | V], head h at col h*64 within each section.
// Q pre-scaled by 0.125*log2(e); softmax in exp2 domain.
// One q-tile per block (2048 blocks, heavy tiles dispatched first) for 6+ blocks/CU.
// S^T via mfma(K,Q): lane owns q=l15; kv = n*16 + lg*4 + r.
// P never touches LDS (kv-permutation absorbed into V staging slot).
// Pipeline: K(t+1) DMA (dbuf Ks) + V(t+1) reg loads in flight across barrier2 (lgkm-only).
__global__ __launch_bounds__(256, 3)
void attn_kernel(const unsigned short* __restrict__ QKV, unsigned short* __restrict__ AO) {
  __shared__ unsigned short Ks[2][64 * 64];
  __shared__ unsigned int Vt32[64 * 36];       // [d][kv-pair slot] packed 2xbf16 per dword

  const int t = threadIdx.x;
  const int l = t & 63;
  const int w = t >> 6;
  const int l15 = l & 15, lg = l >> 4;
  const int id = blockIdx.x;
  const int qt = 31 - (id >> 6);  // heaviest q-tiles dispatched first
  const int bh = id & 63;         // same-head blocks differ by 64 -> same XCD
  const int b = bh >> 4, h = bh & 15;
  const size_t hbase = (size_t)b * SEQ * QKVSTR + h * DK;
  const size_t hbaseO = (size_t)b * SEQ * D_MODEL + h * DK;

  // hoisted Q fragments (MFMA B-operand)
  short8 qf[2];
  {
    const unsigned short* qp = QKV + hbase + (size_t)(qt * 64 + w * 16 + l15) * QKVSTR + lg * 8;
    qf[0] = *(const short8*)qp; qf[1] = *(const short8*)(qp + 32);
  }

  f32x4 o[4] = {};
  float lacc = 0.f;
  float m = -INFINITY;

  // K staging map: thread t covers row srow(+32), 16B chunk sc8; source chunk XOR-swizzled
  const int srow = t >> 3, sc8 = t & 7;
  const int kssw = sc8 ^ (srow & 7);
  // V staging map: thread covers kv-pair vp_, 8 d values; dest slot permuted for register-P PV
  const int vp_ = t & 31;                 // kv-pair index 0..31
  const int vdh = (t >> 5) * 8;           // d offset 0..56
  const int vpos = (vp_ & 17) | ((vp_ & 6) << 1) | ((vp_ & 8) >> 2);  // permuted slot
  const int qrowbase = w * 16 + lg * 4;   // o rows: qt*64 + qrowbase + r

  auto issueK = [&](int kvt, int buf) {
    const unsigned short* kp = QKV + hbase + 1024 + (size_t)(kvt * 64 + srow) * QKVSTR + kssw * 8;
    GLOAD_LDS16(kp, &Ks[buf][srow * 64 + sc8 * 8]);
    GLOAD_LDS16(kp + (size_t)32 * QKVSTR, &Ks[buf][(32 + srow) * 64 + sc8 * 8]);
  };

  const int ntiles = qt + 1;

  // prologue: tile 0 staged
  short8 cv0, cv1;
  issueK(0, 0);
  {
    const unsigned short* vp = QKV + hbase + 2048 + (size_t)(2 * vp_) * QKVSTR + vdh;
    cv0 = *(const short8*)vp;
    cv1 = *(const short8*)(vp + QKVSTR);
  }

  int p = 0;
  for (int kvt = 0; kvt < ntiles; ++kvt) {
    const int kv0 = kvt * 64;
    // barrier1: my K(t) DMA + V(t) regs arrived; all waves done with Vt(t-1) reads
    asm volatile("s_waitcnt vmcnt(0)" ::: "memory");
    __builtin_amdgcn_s_barrier();
    __builtin_amdgcn_sched_barrier(0);

    // stage V(t) to LDS (packed transpose, permuted slot), then prefetch tile t+1
    #pragma unroll
    for (int j = 0; j < 8; ++j) {
      unsigned int dw = (unsigned int)(unsigned short)cv0[j] |
                        ((unsigned int)(unsigned short)cv1[j] << 16);
      Vt32[(vdh + j) * 36 + vpos] = dw;
    }
    short8 nv0 = cv0, nv1 = cv1;
    if (kvt + 1 < ntiles) {
      issueK(kvt + 1, p ^ 1);
      const unsigned short* vp = QKV + hbase + 2048 + (size_t)(kv0 + 64 + 2 * vp_) * QKVSTR + vdh;
      nv0 = *(const short8*)vp;
      nv1 = *(const short8*)(vp + QKVSTR);
    }
    // barrier2: V writes visible; prefetch loads stay in flight (no vmcnt drain)
    asm volatile("s_waitcnt lgkmcnt(0)" ::: "memory");
    __builtin_amdgcn_s_barrier();
    __builtin_amdgcn_sched_barrier(0);

    f32x4 s[4];
    // ---- swapped QK^T ----
    __builtin_amdgcn_s_setprio(1);
    #pragma unroll
    for (int n = 0; n < 4; ++n) {
      int row = n * 16 + l15;
      short8 kf0 = *(const short8*)&Ks[p][row * 64 + ((lg ^ (row & 7)) * 8)];
      short8 kf1 = *(const short8*)&Ks[p][row * 64 + (((4 + lg) ^ (row & 7)) * 8)];
      f32x4 z = {};
      z = __builtin_amdgcn_mfma_f32_16x16x32_bf16(kf0, qf[0], z, 0, 0, 0);
      z = __builtin_amdgcn_mfma_f32_16x16x32_bf16(kf1, qf[1], z, 0, 0, 0);
      s[n] = z;
    }
    __builtin_amdgcn_s_setprio(0);

    // ---- softmax (S^T layout, q=l15 scalar stats), P packed in-register ----
    short8 pa[2];
    {
      const int q = qt * 64 + w * 16 + l15;
      if (kvt == qt) {   // diagonal tile: causal mask
        #pragma unroll
        for (int n = 0; n < 4; ++n)
          #pragma unroll
          for (int r = 0; r < 4; ++r)
            if (kv0 + n * 16 + lg * 4 + r > q) s[n][r] = -INFINITY;
      }
      float pm = -INFINITY;
      #pragma unroll
      for (int n = 0; n < 4; ++n)
        #pragma unroll
        for (int r = 0; r < 4; ++r) pm = fmaxf(pm, s[n][r]);
      pm = fmaxf(pm, __shfl_xor(pm, 16, 64));
      pm = fmaxf(pm, __shfl_xor(pm, 32, 64));
      float mx = fmaxf(m, pm);
      if (!__all(mx - m <= 11.0f)) {     // defer-max: rescale only on real growth
        float al = EXP2(m - mx);
        m = mx;
        lacc *= al;
        float alo[4];
        #pragma unroll
        for (int r = 0; r < 4; ++r) alo[r] = __shfl(al, lg * 4 + r, 64);
        #pragma unroll
        for (int n = 0; n < 4; ++n)
          #pragma unroll
          for (int r = 0; r < 4; ++r) o[n][r] *= alo[r];
      }
      float ps = 0.f;
      unsigned int pw[8];
      #pragma unroll
      for (int n = 0; n < 4; ++n) {
        float p0 = EXP2(s[n][0] - m), p1 = EXP2(s[n][1] - m);
        float p2 = EXP2(s[n][2] - m), p3 = EXP2(s[n][3] - m);
        ps += (p0 + p1) + (p2 + p3);
        pw[n * 2]     = cvt_pk_bf16(p0, p1);
        pw[n * 2 + 1] = cvt_pk_bf16(p2, p3);
      }
      ps += __shfl_xor(ps, 16, 64);
      ps += __shfl_xor(ps, 32, 64);
      lacc += ps;
      uint4 u0 = make_uint4(pw[0], pw[1], pw[2], pw[3]);
      uint4 u1 = make_uint4(pw[4], pw[5], pw[6], pw[7]);
      pa[0] = __builtin_bit_cast(short8, u0);
      pa[1] = __builtin_bit_cast(short8, u1);
    }

    // ---- PV (kv-permuted consistently with pa) ----
    __builtin_amdgcn_s_setprio(1);
    #pragma unroll
    for (int n = 0; n < 4; ++n) {
      int row = n * 16 + l15;
      uint4 u0 = *(const uint4*)&Vt32[row * 36 + lg * 4];
      uint4 u1 = *(const uint4*)&Vt32[row * 36 + 16 + lg * 4];
      o[n] = __builtin_amdgcn_mfma_f32_16x16x32_bf16(pa[0], __builtin_bit_cast(short8, u0), o[n], 0, 0, 0);
      o[n] = __builtin_amdgcn_mfma_f32_16x16x32_bf16(pa[1], __builtin_bit_cast(short8, u1), o[n], 0, 0, 0);
    }
    __builtin_amdgcn_s_setprio(0);

    cv0 = nv0; cv1 = nv1;
    p ^= 1;
  }

  // write normalized output (inv redistributed from q=l15 lanes)
  float inv = 1.f / lacc;
  #pragma unroll
  for (int r = 0; r < 4; ++r) {
    float iv = __shfl(inv, lg * 4 + r, 64);
    unsigned short* op = AO + hbaseO + (size_t)(qt * 64 + qrowbase + r) * D_MODEL;
    #pragma unroll
    for (int n = 0; n < 4; ++n) op[n * 16 + l15] = f2bf(o[n][r] * iv);
  }
}

extern "C" void kernel_launch(void* const* d_in, const int* in_sizes, int n_in,
                              void* d_out, int out_size, void* d_ws, size_t ws_size,
                              hipStream_t stream) {
  const float* x   = (const float*)d_in[0];
  const float* WQw = (const float*)d_in[1];
  const float* WQb = (const float*)d_in[2];
  const float* WKw = (const float*)d_in[3];
  const float* WKb = (const float*)d_in[4];
  const float* WVw = (const float*)d_in[5];
  const float* WVb = (const float*)d_in[6];
  const float* WOw = (const float*)d_in[7];
  const float* WOb = (const float*)d_in[8];
  float* out = (float*)d_out;

  const int M = BATCH * SEQ;       // 8192
  const int D = D_MODEL;           // 1024
  const int NX = M * D;            // 8388608
  const int NW = D * D;            // 1048576

  unsigned short* xb = (unsigned short*)d_ws;
  unsigned short* wq = xb + NX;        // wq|wk|wv|wo contiguous (cvt4)
  unsigned short* wo = wq + 3 * NW;
  unsigned short* QKVb = wq + 4 * NW;  // [8192][3072]
  unsigned short* AOb = xb;            // reuse x-bf16 region after QKV projection

  cvt_kernel<<<NX / 8 / 256, 256, 0, stream>>>(x, xb, NX);
  cvt4_kernel<<<dim3(NW / 8 / 256, 4), 256, 0, stream>>>(WQw, WKw, WVw, WOw, wq, NW);

  const float qscale = 0.125f * 1.4426950408889634f;  // softmax scale + log2(e) folded into Q
  // fused QKV projection: [8192,1024] x [3072,1024]^T -> [8192,3072]
  gemm_bt<unsigned short><<<dim3(3 * D / 128, M / 128), 256, 0, stream>>>(
      xb, wq, WQb, WKb, WVb, QKVb, M, 3 * D, D, 1024, qscale);

  attn_kernel<<<2048, 256, 0, stream>>>(QKVb, AOb);

  gemm_bt<float><<<dim3(D / 128, M / 128), 256, 0, stream>>>(
      AOb, wo, WOb, WOb, WOb, out, M, D, D, 0, 1.0f);
}

// Round 13
// 167.400 us; speedup vs baseline: 1.3845x; 1.1126x over previous
//
#include <hip/hip_runtime.h>
#include <hip/hip_bf16.h>
#include <stdint.h>

#define D_MODEL 1024
#define NHEAD 16
#define SEQ 2048
#define BATCH 4
#define DK 64
#define QKVSTR 3072

typedef __attribute__((ext_vector_type(8))) short short8;
typedef __attribute__((ext_vector_type(4))) float f32x4;

#if __has_builtin(__builtin_amdgcn_exp2f)
#define EXP2(x) __builtin_amdgcn_exp2f(x)
#else
#define EXP2(x) exp2f(x)
#endif

__device__ inline unsigned short f2bf(float f) {
  unsigned int u = __builtin_bit_cast(unsigned int, f);
  unsigned int r = (u + 0x7fffu + ((u >> 16) & 1u)) >> 16;
  return (unsigned short)r;
}

__device__ inline unsigned int cvt_pk_bf16(float lo, float hi) {
  unsigned int d;
  asm("v_cvt_pk_bf16_f32 %0, %1, %2" : "=v"(d) : "v"(lo), "v"(hi));
  return d;
}

#define GLOAD_LDS16(g, l) \
  __builtin_amdgcn_global_load_lds((const __attribute__((address_space(1))) unsigned int*)(g), \
      (__attribute__((address_space(3))) unsigned int*)(l), 16, 0, 0)

// ---------------- f32 -> bf16 convert ----------------
__global__ void cvt_kernel(const float* __restrict__ in, unsigned short* __restrict__ out, int n) {
  int i = (blockIdx.x * 256 + threadIdx.x) * 8;
  if (i >= n) return;
  const float4* p = (const float4*)(in + i);
  float4 a = p[0], b = p[1];
  union { unsigned short u[8]; uint4 v; } r;
  r.u[0] = f2bf(a.x); r.u[1] = f2bf(a.y); r.u[2] = f2bf(a.z); r.u[3] = f2bf(a.w);
  r.u[4] = f2bf(b.x); r.u[5] = f2bf(b.y); r.u[6] = f2bf(b.z); r.u[7] = f2bf(b.w);
  *(uint4*)(out + i) = r.v;
}

// 4 weight matrices in one dispatch; outputs contiguous at out + by*n
__global__ void cvt4_kernel(const float* __restrict__ i0, const float* __restrict__ i1,
                            const float* __restrict__ i2, const float* __restrict__ i3,
                            unsigned short* __restrict__ out, int n) {
  const int by = blockIdx.y;
  const float* in = (by == 0) ? i0 : (by == 1) ? i1 : (by == 2) ? i2 : i3;
  unsigned short* o = out + (size_t)by * n;
  int i = (blockIdx.x * 256 + threadIdx.x) * 8;
  if (i >= n) return;
  const float4* p = (const float4*)(in + i);
  float4 a = p[0], b = p[1];
  union { unsigned short u[8]; uint4 v; } r;
  r.u[0] = f2bf(a.x); r.u[1] = f2bf(a.y); r.u[2] = f2bf(a.z); r.u[3] = f2bf(a.w);
  r.u[4] = f2bf(b.x); r.u[5] = f2bf(b.y); r.u[6] = f2bf(b.z); r.u[7] = f2bf(b.w);
  *(uint4*)(o + i) = r.v;
}

// ---------------- GEMM: C[M,N] = f(A[M,K] * B[N,K]^T + bias) ----------------
// 2-phase overlapped: double-buffered LDS, STAGE(t+1) issued before compute(t),
// single vmcnt(0)+barrier per K-step. A/B staged with per-8-row XOR chunk swizzle
// (pre-swizzled global source, linear LDS dest) -> conflict-free fragment reads.
// bias selected per 1024-column section from b0/b1/b2; cols < qcols scaled by alphaQ.
template <typename CT>
__global__ __launch_bounds__(256)
void gemm_bt(const unsigned short* __restrict__ A, const unsigned short* __restrict__ B,
             const float* __restrict__ b0, const float* __restrict__ b1,
             const float* __restrict__ b2, CT* __restrict__ C, int M, int N, int K,
             int qcols, float alphaQ) {
  __shared__ unsigned short As[2][128 * 64];
  __shared__ unsigned short Bs[2][128 * 64];
  const int t = threadIdx.x;
  const int l = t & 63;
  const int w = t >> 6;
  const int wr = w >> 1, wc = w & 1;
  const int l15 = l & 15, lg = l >> 4;
  const int m0 = blockIdx.y * 128, n0 = blockIdx.x * 128;

  f32x4 acc[4][4] = {};

  const int srow = t >> 3;           // 0..31
  const int sc8 = t & 7;             // dest 16B chunk
  const int kssw = sc8 ^ (srow & 7); // XOR-swizzled source chunk

  auto STAGE = [&](int buf, int k0) {
    const unsigned short* ap = A + (size_t)(m0 + srow) * K + k0 + kssw * 8;
    const unsigned short* bp = B + (size_t)(n0 + srow) * K + k0 + kssw * 8;
    #pragma unroll
    for (int j = 0; j < 4; ++j) {
      GLOAD_LDS16(ap + (size_t)(j * 32) * K, &As[buf][(j * 32 + srow) * 64 + sc8 * 8]);
      GLOAD_LDS16(bp + (size_t)(j * 32) * K, &Bs[buf][(j * 32 + srow) * 64 + sc8 * 8]);
    }
  };

  const int nt = K >> 6;
  STAGE(0, 0);
  asm volatile("s_waitcnt vmcnt(0)" ::: "memory");
  __builtin_amdgcn_s_barrier();
  __builtin_amdgcn_sched_barrier(0);

  int buf = 0;
  for (int kt = 0; kt < nt; ++kt) {
    if (kt + 1 < nt) STAGE(buf ^ 1, (kt + 1) * 64);

    __builtin_amdgcn_s_setprio(1);
    #pragma unroll
    for (int kk = 0; kk < 2; ++kk) {
      short8 af[4], bfr[4];
      #pragma unroll
      for (int m = 0; m < 4; ++m) {
        int row = wr * 64 + m * 16 + l15;
        af[m] = *(const short8*)&As[buf][row * 64 + (((kk * 4 + lg) ^ (row & 7)) * 8)];
      }
      #pragma unroll
      for (int n = 0; n < 4; ++n) {
        int row = wc * 64 + n * 16 + l15;
        bfr[n] = *(const short8*)&Bs[buf][row * 64 + (((kk * 4 + lg) ^ (row & 7)) * 8)];
      }
      #pragma unroll
      for (int m = 0; m < 4; ++m)
        #pragma unroll
        for (int n = 0; n < 4; ++n)
          acc[m][n] = __builtin_amdgcn_mfma_f32_16x16x32_bf16(af[m], bfr[n], acc[m][n], 0, 0, 0);
    }
    __builtin_amdgcn_s_setprio(0);

    // next tile's loads complete; all waves done reading buf
    asm volatile("s_waitcnt vmcnt(0)" ::: "memory");
    __builtin_amdgcn_s_barrier();
    __builtin_amdgcn_sched_barrier(0);
    buf ^= 1;
  }

  #pragma unroll
  for (int m = 0; m < 4; ++m) {
    #pragma unroll
    for (int n = 0; n < 4; ++n) {
      int col = n0 + wc * 64 + n * 16 + l15;
      const float* bp = (col < 1024) ? b0 : (col < 2048) ? b1 : b2;
      float bz = bp[col & 1023];
      #pragma unroll
      for (int r = 0; r < 4; ++r) {
        int row = m0 + wr * 64 + m * 16 + lg * 4 + r;
        float v = acc[m][n][r] + bz;
        if (col < qcols) v *= alphaQ;
        if constexpr (sizeof(CT) == 2) {
          C[(size_t)row * N + col] = (CT)f2bf(v);
        } else {
          C[(size_t)row * N + col] = v;
        }
      }
    }
  }
}

// ---------------- causal flash attention: unpaired, swapped QK^T, register-P ----------------
// QKV: [B*S, 3072] bf16 rows = [Q | K | V], head h at col h*64 within each section.
// Q pre-scaled by 0.125*log2(e); softmax in exp2 domain.
// One q-tile per block (2048 blocks, heavy tiles dispatched first) for 6+ blocks/CU.
// S^T via mfma(K,Q): lane owns q=l15; kv = n*16 + lg*4 + r.
// P never touches LDS (kv-permutation absorbed into V staging slot).
// Pipeline: K(t+1) DMA (dbuf Ks) + V(t+1) reg loads in flight across barrier2 (lgkm-only).
__global__ __launch_bounds__(256, 3)
void attn_kernel(const unsigned short* __restrict__ QKV, unsigned short* __restrict__ AO) {
  __shared__ unsigned short Ks[2][64 * 64];
  __shared__ unsigned int Vt32[64 * 36];       // [d][kv-pair slot] packed 2xbf16 per dword

  const int t = threadIdx.x;
  const int l = t & 63;
  const int w = t >> 6;
  const int l15 = l & 15, lg = l >> 4;
  const int id = blockIdx.x;
  const int qt = 31 - (id >> 6);  // heaviest q-tiles dispatched first
  const int bh = id & 63;         // same-head blocks differ by 64 -> same XCD
  const int b = bh >> 4, h = bh & 15;
  const size_t hbase = (size_t)b * SEQ * QKVSTR + h * DK;
  const size_t hbaseO = (size_t)b * SEQ * D_MODEL + h * DK;

  // hoisted Q fragments (MFMA B-operand)
  short8 qf[2];
  {
    const unsigned short* qp = QKV + hbase + (size_t)(qt * 64 + w * 16 + l15) * QKVSTR + lg * 8;
    qf[0] = *(const short8*)qp; qf[1] = *(const short8*)(qp + 32);
  }

  f32x4 o[4] = {};
  float lacc = 0.f;
  float m = -INFINITY;

  // K staging map: thread t covers row srow(+32), 16B chunk sc8; source chunk XOR-swizzled
  const int srow = t >> 3, sc8 = t & 7;
  const int kssw = sc8 ^ (srow & 7);
  // V staging map: thread covers kv-pair vp_, 8 d values; dest slot permuted for register-P PV
  const int vp_ = t & 31;                 // kv-pair index 0..31
  const int vdh = (t >> 5) * 8;           // d offset 0..56
  const int vpos = (vp_ & 17) | ((vp_ & 6) << 1) | ((vp_ & 8) >> 2);  // permuted slot
  const int qrowbase = w * 16 + lg * 4;   // o rows: qt*64 + qrowbase + r

  auto issueK = [&](int kvt, int buf) {
    const unsigned short* kp = QKV + hbase + 1024 + (size_t)(kvt * 64 + srow) * QKVSTR + kssw * 8;
    GLOAD_LDS16(kp, &Ks[buf][srow * 64 + sc8 * 8]);
    GLOAD_LDS16(kp + (size_t)32 * QKVSTR, &Ks[buf][(32 + srow) * 64 + sc8 * 8]);
  };

  const int ntiles = qt + 1;

  // prologue: tile 0 staged
  short8 cv0, cv1;
  issueK(0, 0);
  {
    const unsigned short* vp = QKV + hbase + 2048 + (size_t)(2 * vp_) * QKVSTR + vdh;
    cv0 = *(const short8*)vp;
    cv1 = *(const short8*)(vp + QKVSTR);
  }

  int p = 0;
  for (int kvt = 0; kvt < ntiles; ++kvt) {
    const int kv0 = kvt * 64;
    // barrier1: my K(t) DMA + V(t) regs arrived; all waves done with Vt(t-1) reads
    asm volatile("s_waitcnt vmcnt(0)" ::: "memory");
    __builtin_amdgcn_s_barrier();
    __builtin_amdgcn_sched_barrier(0);

    // stage V(t) to LDS (packed transpose, permuted slot), then prefetch tile t+1
    #pragma unroll
    for (int j = 0; j < 8; ++j) {
      unsigned int dw = (unsigned int)(unsigned short)cv0[j] |
                        ((unsigned int)(unsigned short)cv1[j] << 16);
      Vt32[(vdh + j) * 36 + vpos] = dw;
    }
    short8 nv0 = cv0, nv1 = cv1;
    if (kvt + 1 < ntiles) {
      issueK(kvt + 1, p ^ 1);
      const unsigned short* vp = QKV + hbase + 2048 + (size_t)(kv0 + 64 + 2 * vp_) * QKVSTR + vdh;
      nv0 = *(const short8*)vp;
      nv1 = *(const short8*)(vp + QKVSTR);
    }
    // barrier2: V writes visible; prefetch loads stay in flight (no vmcnt drain)
    asm volatile("s_waitcnt lgkmcnt(0)" ::: "memory");
    __builtin_amdgcn_s_barrier();
    __builtin_amdgcn_sched_barrier(0);

    f32x4 s[4];
    // ---- swapped QK^T ----
    __builtin_amdgcn_s_setprio(1);
    #pragma unroll
    for (int n = 0; n < 4; ++n) {
      int row = n * 16 + l15;
      short8 kf0 = *(const short8*)&Ks[p][row * 64 + ((lg ^ (row & 7)) * 8)];
      short8 kf1 = *(const short8*)&Ks[p][row * 64 + (((4 + lg) ^ (row & 7)) * 8)];
      f32x4 z = {};
      z = __builtin_amdgcn_mfma_f32_16x16x32_bf16(kf0, qf[0], z, 0, 0, 0);
      z = __builtin_amdgcn_mfma_f32_16x16x32_bf16(kf1, qf[1], z, 0, 0, 0);
      s[n] = z;
    }
    __builtin_amdgcn_s_setprio(0);

    // ---- softmax (S^T layout, q=l15 scalar stats), P packed in-register ----
    short8 pa[2];
    {
      const int q = qt * 64 + w * 16 + l15;
      if (kvt == qt) {   // diagonal tile: causal mask
        #pragma unroll
        for (int n = 0; n < 4; ++n)
          #pragma unroll
          for (int r = 0; r < 4; ++r)
            if (kv0 + n * 16 + lg * 4 + r > q) s[n][r] = -INFINITY;
      }
      float pm = -INFINITY;
      #pragma unroll
      for (int n = 0; n < 4; ++n)
        #pragma unroll
        for (int r = 0; r < 4; ++r) pm = fmaxf(pm, s[n][r]);
      pm = fmaxf(pm, __shfl_xor(pm, 16, 64));
      pm = fmaxf(pm, __shfl_xor(pm, 32, 64));
      float mx = fmaxf(m, pm);
      if (!__all(mx - m <= 11.0f)) {     // defer-max: rescale only on real growth
        float al = EXP2(m - mx);
        m = mx;
        lacc *= al;
        float alo[4];
        #pragma unroll
        for (int r = 0; r < 4; ++r) alo[r] = __shfl(al, lg * 4 + r, 64);
        #pragma unroll
        for (int n = 0; n < 4; ++n)
          #pragma unroll
          for (int r = 0; r < 4; ++r) o[n][r] *= alo[r];
      }
      float ps = 0.f;
      unsigned int pw[8];
      #pragma unroll
      for (int n = 0; n < 4; ++n) {
        float p0 = EXP2(s[n][0] - m), p1 = EXP2(s[n][1] - m);
        float p2 = EXP2(s[n][2] - m), p3 = EXP2(s[n][3] - m);
        ps += (p0 + p1) + (p2 + p3);
        pw[n * 2]     = cvt_pk_bf16(p0, p1);
        pw[n * 2 + 1] = cvt_pk_bf16(p2, p3);
      }
      ps += __shfl_xor(ps, 16, 64);
      ps += __shfl_xor(ps, 32, 64);
      lacc += ps;
      uint4 u0 = make_uint4(pw[0], pw[1], pw[2], pw[3]);
      uint4 u1 = make_uint4(pw[4], pw[5], pw[6], pw[7]);
      pa[0] = __builtin_bit_cast(short8, u0);
      pa[1] = __builtin_bit_cast(short8, u1);
    }

    // ---- PV (kv-permuted consistently with pa) ----
    __builtin_amdgcn_s_setprio(1);
    #pragma unroll
    for (int n = 0; n < 4; ++n) {
      int row = n * 16 + l15;
      uint4 u0 = *(const uint4*)&Vt32[row * 36 + lg * 4];
      uint4 u1 = *(const uint4*)&Vt32[row * 36 + 16 + lg * 4];
      o[n] = __builtin_amdgcn_mfma_f32_16x16x32_bf16(pa[0], __builtin_bit_cast(short8, u0), o[n], 0, 0, 0);
      o[n] = __builtin_amdgcn_mfma_f32_16x16x32_bf16(pa[1], __builtin_bit_cast(short8, u1), o[n], 0, 0, 0);
    }
    __builtin_amdgcn_s_setprio(0);

    cv0 = nv0; cv1 = nv1;
    p ^= 1;
  }

  // write normalized output (inv redistributed from q=l15 lanes)
  float inv = 1.f / lacc;
  #pragma unroll
  for (int r = 0; r < 4; ++r) {
    float iv = __shfl(inv, lg * 4 + r, 64);
    unsigned short* op = AO + hbaseO + (size_t)(qt * 64 + qrowbase + r) * D_MODEL;
    #pragma unroll
    for (int n = 0; n < 4; ++n) op[n * 16 + l15] = f2bf(o[n][r] * iv);
  }
}

extern "C" void kernel_launch(void* const* d_in, const int* in_sizes, int n_in,
                              void* d_out, int out_size, void* d_ws, size_t ws_size,
                              hipStream_t stream) {
  const float* x   = (const float*)d_in[0];
  const float* WQw = (const float*)d_in[1];
  const float* WQb = (const float*)d_in[2];
  const float* WKw = (const float*)d_in[3];
  const float* WKb = (const float*)d_in[4];
  const float* WVw = (const float*)d_in[5];
  const float* WVb = (const float*)d_in[6];
  const float* WOw = (const float*)d_in[7];
  const float* WOb = (const float*)d_in[8];
  float* out = (float*)d_out;

  const int M = BATCH * SEQ;       // 8192
  const int D = D_MODEL;           // 1024
  const int NX = M * D;            // 8388608
  const int NW = D * D;            // 1048576

  unsigned short* xb = (unsigned short*)d_ws;
  unsigned short* wq = xb + NX;        // wq|wk|wv|wo contiguous (cvt4)
  unsigned short* wo = wq + 3 * NW;
  unsigned short* QKVb = wq + 4 * NW;  // [8192][3072]
  unsigned short* AOb = xb;            // reuse x-bf16 region after QKV projection

  cvt_kernel<<<NX / 8 / 256, 256, 0, stream>>>(x, xb, NX);
  cvt4_kernel<<<dim3(NW / 8 / 256, 4), 256, 0, stream>>>(WQw, WKw, WVw, WOw, wq, NW);

  const float qscale = 0.125f * 1.4426950408889634f;  // softmax scale + log2(e) folded into Q
  // fused QKV projection: [8192,1024] x [3072,1024]^T -> [8192,3072]
  gemm_bt<unsigned short><<<dim3(3 * D / 128, M / 128), 256, 0, stream>>>(
      xb, wq, WQb, WKb, WVb, QKVb, M, 3 * D, D, 1024, qscale);

  attn_kernel<<<2048, 256, 0, stream>>>(QKVb, AOb);

  gemm_bt<float><<<dim3(D / 128, M / 128), 256, 0, stream>>>(
      AOb, wo, WOb, WOb, WOb, out, M, D, D, 0, 1.0f);
}

// Round 14
// 160.500 us; speedup vs baseline: 1.4440x; 1.0430x over previous
//
#include <hip/hip_runtime.h>
#include <hip/hip_bf16.h>
#include <stdint.h>

#define D_MODEL 1024
#define NHEAD 16
#define SEQ 2048
#define BATCH 4
#define DK 64
#define QKVSTR 3072

typedef __attribute__((ext_vector_type(8))) short short8;
typedef __attribute__((ext_vector_type(4))) float f32x4;

#if __has_builtin(__builtin_amdgcn_exp2f)
#define EXP2(x) __builtin_amdgcn_exp2f(x)
#else
#define EXP2(x) exp2f(x)
#endif

__device__ inline unsigned short f2bf(float f) {
  unsigned int u = __builtin_bit_cast(unsigned int, f);
  unsigned int r = (u + 0x7fffu + ((u >> 16) & 1u)) >> 16;
  return (unsigned short)r;
}

__device__ inline unsigned int cvt_pk_bf16(float lo, float hi) {
  unsigned int d;
  asm("v_cvt_pk_bf16_f32 %0, %1, %2" : "=v"(d) : "v"(lo), "v"(hi));
  return d;
}

#define GLOAD_LDS16(g, l) \
  __builtin_amdgcn_global_load_lds((const __attribute__((address_space(1))) unsigned int*)(g), \
      (__attribute__((address_space(3))) unsigned int*)(l), 16, 0, 0)

// ---------------- f32 -> bf16 convert ----------------
__global__ void cvt_kernel(const float* __restrict__ in, unsigned short* __restrict__ out, int n) {
  int i = (blockIdx.x * 256 + threadIdx.x) * 8;
  if (i >= n) return;
  const float4* p = (const float4*)(in + i);
  float4 a = p[0], b = p[1];
  union { unsigned short u[8]; uint4 v; } r;
  r.u[0] = f2bf(a.x); r.u[1] = f2bf(a.y); r.u[2] = f2bf(a.z); r.u[3] = f2bf(a.w);
  r.u[4] = f2bf(b.x); r.u[5] = f2bf(b.y); r.u[6] = f2bf(b.z); r.u[7] = f2bf(b.w);
  *(uint4*)(out + i) = r.v;
}

// 4 weight matrices in one dispatch; outputs contiguous at out + by*n
__global__ void cvt4_kernel(const float* __restrict__ i0, const float* __restrict__ i1,
                            const float* __restrict__ i2, const float* __restrict__ i3,
                            unsigned short* __restrict__ out, int n) {
  const int by = blockIdx.y;
  const float* in = (by == 0) ? i0 : (by == 1) ? i1 : (by == 2) ? i2 : i3;
  unsigned short* o = out + (size_t)by * n;
  int i = (blockIdx.x * 256 + threadIdx.x) * 8;
  if (i >= n) return;
  const float4* p = (const float4*)(in + i);
  float4 a = p[0], b = p[1];
  union { unsigned short u[8]; uint4 v; } r;
  r.u[0] = f2bf(a.x); r.u[1] = f2bf(a.y); r.u[2] = f2bf(a.z); r.u[3] = f2bf(a.w);
  r.u[4] = f2bf(b.x); r.u[5] = f2bf(b.y); r.u[6] = f2bf(b.z); r.u[7] = f2bf(b.w);
  *(uint4*)(o + i) = r.v;
}

// ---------------- GEMM: C[M,N] = f(A[M,K] * B[N,K]^T + bias) ----------------
// m97-style: single 32KB LDS buffer (5 blocks/CU -> cross-block overlap hides the
// barrier drain), stage -> vmcnt(0)+barrier -> 32 MFMA -> barrier per K-step.
// A/B staged with per-8-row XOR chunk swizzle (pre-swizzled global source, linear
// LDS dest) -> conflict-free fragment reads.
// bias selected per 1024-column section from b0/b1/b2; cols < qcols scaled by alphaQ.
template <typename CT>
__global__ __launch_bounds__(256)
void gemm_bt(const unsigned short* __restrict__ A, const unsigned short* __restrict__ B,
             const float* __restrict__ b0, const float* __restrict__ b1,
             const float* __restrict__ b2, CT* __restrict__ C, int M, int N, int K,
             int qcols, float alphaQ) {
  __shared__ unsigned short As[128 * 64];
  __shared__ unsigned short Bs[128 * 64];
  const int t = threadIdx.x;
  const int l = t & 63;
  const int w = t >> 6;
  const int wr = w >> 1, wc = w & 1;
  const int l15 = l & 15, lg = l >> 4;
  const int m0 = blockIdx.y * 128, n0 = blockIdx.x * 128;

  f32x4 acc[4][4] = {};

  const int srow = t >> 3;           // 0..31
  const int sc8 = t & 7;             // dest 16B chunk
  const int kssw = sc8 ^ (srow & 7); // XOR-swizzled source chunk

  const unsigned short* ap = A + (size_t)(m0 + srow) * K + kssw * 8;
  const unsigned short* bp = B + (size_t)(n0 + srow) * K + kssw * 8;

  const int nt = K >> 6;
  for (int kt = 0; kt < nt; ++kt) {
    const int k0 = kt * 64;
    #pragma unroll
    for (int j = 0; j < 4; ++j) {
      GLOAD_LDS16(ap + (size_t)(j * 32) * K + k0, &As[(j * 32 + srow) * 64 + sc8 * 8]);
      GLOAD_LDS16(bp + (size_t)(j * 32) * K + k0, &Bs[(j * 32 + srow) * 64 + sc8 * 8]);
    }
    asm volatile("s_waitcnt vmcnt(0)" ::: "memory");
    __builtin_amdgcn_s_barrier();
    __builtin_amdgcn_sched_barrier(0);

    __builtin_amdgcn_s_setprio(1);
    #pragma unroll
    for (int kk = 0; kk < 2; ++kk) {
      short8 af[4], bfr[4];
      #pragma unroll
      for (int m = 0; m < 4; ++m) {
        int row = wr * 64 + m * 16 + l15;
        af[m] = *(const short8*)&As[row * 64 + (((kk * 4 + lg) ^ (row & 7)) * 8)];
      }
      #pragma unroll
      for (int n = 0; n < 4; ++n) {
        int row = wc * 64 + n * 16 + l15;
        bfr[n] = *(const short8*)&Bs[row * 64 + (((kk * 4 + lg) ^ (row & 7)) * 8)];
      }
      #pragma unroll
      for (int m = 0; m < 4; ++m)
        #pragma unroll
        for (int n = 0; n < 4; ++n)
          acc[m][n] = __builtin_amdgcn_mfma_f32_16x16x32_bf16(af[m], bfr[n], acc[m][n], 0, 0, 0);
    }
    __builtin_amdgcn_s_setprio(0);

    // all waves done reading As/Bs before next iteration's DMA overwrites them
    __builtin_amdgcn_s_barrier();
    __builtin_amdgcn_sched_barrier(0);
  }

  #pragma unroll
  for (int m = 0; m < 4; ++m) {
    #pragma unroll
    for (int n = 0; n < 4; ++n) {
      int col = n0 + wc * 64 + n * 16 + l15;
      const float* bp2 = (col < 1024) ? b0 : (col < 2048) ? b1 : b2;
      float bz = bp2[col & 1023];
      #pragma unroll
      for (int r = 0; r < 4; ++r) {
        int row = m0 + wr * 64 + m * 16 + lg * 4 + r;
        float v = acc[m][n][r] + bz;
        if (col < qcols) v *= alphaQ;
        if constexpr (sizeof(CT) == 2) {
          C[(size_t)row * N + col] = (CT)f2bf(v);
        } else {
          C[(size_t)row * N + col] = v;
        }
      }
    }
  }
}

// ---------------- causal flash attention: unpaired, swapped QK^T, register-P ----------------
// QKV: [B*S, 3072] bf16 rows = [Q | K | V], head h at col h*64 within each section.
// Q pre-scaled by 0.125*log2(e); softmax in exp2 domain.
// One q-tile per block (2048 blocks, heavy tiles dispatched first) for 6+ blocks/CU.
// S^T via mfma(K,Q): lane owns q=l15; kv = n*16 + lg*4 + r.
// P never touches LDS (kv-permutation absorbed into V staging slot).
// Pipeline: K(t+1) DMA (dbuf Ks) + V(t+1) reg loads in flight across barrier2 (lgkm-only).
__global__ __launch_bounds__(256, 3)
void attn_kernel(const unsigned short* __restrict__ QKV, unsigned short* __restrict__ AO) {
  __shared__ unsigned short Ks[2][64 * 64];
  __shared__ unsigned int Vt32[64 * 36];       // [d][kv-pair slot] packed 2xbf16 per dword

  const int t = threadIdx.x;
  const int l = t & 63;
  const int w = t >> 6;
  const int l15 = l & 15, lg = l >> 4;
  const int id = blockIdx.x;
  const int qt = 31 - (id >> 6);  // heaviest q-tiles dispatched first
  const int bh = id & 63;         // same-head blocks differ by 64 -> same XCD
  const int b = bh >> 4, h = bh & 15;
  const size_t hbase = (size_t)b * SEQ * QKVSTR + h * DK;
  const size_t hbaseO = (size_t)b * SEQ * D_MODEL + h * DK;

  // hoisted Q fragments (MFMA B-operand)
  short8 qf[2];
  {
    const unsigned short* qp = QKV + hbase + (size_t)(qt * 64 + w * 16 + l15) * QKVSTR + lg * 8;
    qf[0] = *(const short8*)qp; qf[1] = *(const short8*)(qp + 32);
  }

  f32x4 o[4] = {};
  float lacc = 0.f;
  float m = -INFINITY;

  // K staging map: thread t covers row srow(+32), 16B chunk sc8; source chunk XOR-swizzled
  const int srow = t >> 3, sc8 = t & 7;
  const int kssw = sc8 ^ (srow & 7);
  // V staging map: thread covers kv-pair vp_, 8 d values; dest slot permuted for register-P PV
  const int vp_ = t & 31;                 // kv-pair index 0..31
  const int vdh = (t >> 5) * 8;           // d offset 0..56
  const int vpos = (vp_ & 17) | ((vp_ & 6) << 1) | ((vp_ & 8) >> 2);  // permuted slot
  const int qrowbase = w * 16 + lg * 4;   // o rows: qt*64 + qrowbase + r

  auto issueK = [&](int kvt, int buf) {
    const unsigned short* kp = QKV + hbase + 1024 + (size_t)(kvt * 64 + srow) * QKVSTR + kssw * 8;
    GLOAD_LDS16(kp, &Ks[buf][srow * 64 + sc8 * 8]);
    GLOAD_LDS16(kp + (size_t)32 * QKVSTR, &Ks[buf][(32 + srow) * 64 + sc8 * 8]);
  };

  const int ntiles = qt + 1;

  // prologue: tile 0 staged
  short8 cv0, cv1;
  issueK(0, 0);
  {
    const unsigned short* vp = QKV + hbase + 2048 + (size_t)(2 * vp_) * QKVSTR + vdh;
    cv0 = *(const short8*)vp;
    cv1 = *(const short8*)(vp + QKVSTR);
  }

  int p = 0;
  for (int kvt = 0; kvt < ntiles; ++kvt) {
    const int kv0 = kvt * 64;
    // barrier1: my K(t) DMA + V(t) regs arrived; all waves done with Vt(t-1) reads
    asm volatile("s_waitcnt vmcnt(0)" ::: "memory");
    __builtin_amdgcn_s_barrier();
    __builtin_amdgcn_sched_barrier(0);

    // stage V(t) to LDS (packed transpose, permuted slot), then prefetch tile t+1
    #pragma unroll
    for (int j = 0; j < 8; ++j) {
      unsigned int dw = (unsigned int)(unsigned short)cv0[j] |
                        ((unsigned int)(unsigned short)cv1[j] << 16);
      Vt32[(vdh + j) * 36 + vpos] = dw;
    }
    short8 nv0 = cv0, nv1 = cv1;
    if (kvt + 1 < ntiles) {
      issueK(kvt + 1, p ^ 1);
      const unsigned short* vp = QKV + hbase + 2048 + (size_t)(kv0 + 64 + 2 * vp_) * QKVSTR + vdh;
      nv0 = *(const short8*)vp;
      nv1 = *(const short8*)(vp + QKVSTR);
    }
    // barrier2: V writes visible; prefetch loads stay in flight (no vmcnt drain)
    asm volatile("s_waitcnt lgkmcnt(0)" ::: "memory");
    __builtin_amdgcn_s_barrier();
    __builtin_amdgcn_sched_barrier(0);

    f32x4 s[4];
    // ---- swapped QK^T ----
    __builtin_amdgcn_s_setprio(1);
    #pragma unroll
    for (int n = 0; n < 4; ++n) {
      int row = n * 16 + l15;
      short8 kf0 = *(const short8*)&Ks[p][row * 64 + ((lg ^ (row & 7)) * 8)];
      short8 kf1 = *(const short8*)&Ks[p][row * 64 + (((4 + lg) ^ (row & 7)) * 8)];
      f32x4 z = {};
      z = __builtin_amdgcn_mfma_f32_16x16x32_bf16(kf0, qf[0], z, 0, 0, 0);
      z = __builtin_amdgcn_mfma_f32_16x16x32_bf16(kf1, qf[1], z, 0, 0, 0);
      s[n] = z;
    }
    __builtin_amdgcn_s_setprio(0);

    // ---- softmax (S^T layout, q=l15 scalar stats), P packed in-register ----
    short8 pa[2];
    {
      const int q = qt * 64 + w * 16 + l15;
      if (kvt == qt) {   // diagonal tile: causal mask
        #pragma unroll
        for (int n = 0; n < 4; ++n)
          #pragma unroll
          for (int r = 0; r < 4; ++r)
            if (kv0 + n * 16 + lg * 4 + r > q) s[n][r] = -INFINITY;
      }
      float pm = -INFINITY;
      #pragma unroll
      for (int n = 0; n < 4; ++n)
        #pragma unroll
        for (int r = 0; r < 4; ++r) pm = fmaxf(pm, s[n][r]);
      pm = fmaxf(pm, __shfl_xor(pm, 16, 64));
      pm = fmaxf(pm, __shfl_xor(pm, 32, 64));
      float mx = fmaxf(m, pm);
      if (!__all(mx - m <= 11.0f)) {     // defer-max: rescale only on real growth
        float al = EXP2(m - mx);
        m = mx;
        lacc *= al;
        float alo[4];
        #pragma unroll
        for (int r = 0; r < 4; ++r) alo[r] = __shfl(al, lg * 4 + r, 64);
        #pragma unroll
        for (int n = 0; n < 4; ++n)
          #pragma unroll
          for (int r = 0; r < 4; ++r) o[n][r] *= alo[r];
      }
      float ps = 0.f;
      unsigned int pw[8];
      #pragma unroll
      for (int n = 0; n < 4; ++n) {
        float p0 = EXP2(s[n][0] - m), p1 = EXP2(s[n][1] - m);
        float p2 = EXP2(s[n][2] - m), p3 = EXP2(s[n][3] - m);
        ps += (p0 + p1) + (p2 + p3);
        pw[n * 2]     = cvt_pk_bf16(p0, p1);
        pw[n * 2 + 1] = cvt_pk_bf16(p2, p3);
      }
      ps += __shfl_xor(ps, 16, 64);
      ps += __shfl_xor(ps, 32, 64);
      lacc += ps;
      uint4 u0 = make_uint4(pw[0], pw[1], pw[2], pw[3]);
      uint4 u1 = make_uint4(pw[4], pw[5], pw[6], pw[7]);
      pa[0] = __builtin_bit_cast(short8, u0);
      pa[1] = __builtin_bit_cast(short8, u1);
    }

    // ---- PV (kv-permuted consistently with pa) ----
    __builtin_amdgcn_s_setprio(1);
    #pragma unroll
    for (int n = 0; n < 4; ++n) {
      int row = n * 16 + l15;
      uint4 u0 = *(const uint4*)&Vt32[row * 36 + lg * 4];
      uint4 u1 = *(const uint4*)&Vt32[row * 36 + 16 + lg * 4];
      o[n] = __builtin_amdgcn_mfma_f32_16x16x32_bf16(pa[0], __builtin_bit_cast(short8, u0), o[n], 0, 0, 0);
      o[n] = __builtin_amdgcn_mfma_f32_16x16x32_bf16(pa[1], __builtin_bit_cast(short8, u1), o[n], 0, 0, 0);
    }
    __builtin_amdgcn_s_setprio(0);

    cv0 = nv0; cv1 = nv1;
    p ^= 1;
  }

  // write normalized output (inv redistributed from q=l15 lanes)
  float inv = 1.f / lacc;
  #pragma unroll
  for (int r = 0; r < 4; ++r) {
    float iv = __shfl(inv, lg * 4 + r, 64);
    unsigned short* op = AO + hbaseO + (size_t)(qt * 64 + qrowbase + r) * D_MODEL;
    #pragma unroll
    for (int n = 0; n < 4; ++n) op[n * 16 + l15] = f2bf(o[n][r] * iv);
  }
}

extern "C" void kernel_launch(void* const* d_in, const int* in_sizes, int n_in,
                              void* d_out, int out_size, void* d_ws, size_t ws_size,
                              hipStream_t stream) {
  const float* x   = (const float*)d_in[0];
  const float* WQw = (const float*)d_in[1];
  const float* WQb = (const float*)d_in[2];
  const float* WKw = (const float*)d_in[3];
  const float* WKb = (const float*)d_in[4];
  const float* WVw = (const float*)d_in[5];
  const float* WVb = (const float*)d_in[6];
  const float* WOw = (const float*)d_in[7];
  const float* WOb = (const float*)d_in[8];
  float* out = (float*)d_out;

  const int M = BATCH * SEQ;       // 8192
  const int D = D_MODEL;           // 1024
  const int NX = M * D;            // 8388608
  const int NW = D * D;            // 1048576

  unsigned short* xb = (unsigned short*)d_ws;
  unsigned short* wq = xb + NX;        // wq|wk|wv|wo contiguous (cvt4)
  unsigned short* wo = wq + 3 * NW;
  unsigned short* QKVb = wq + 4 * NW;  // [8192][3072]
  unsigned short* AOb = xb;            // reuse x-bf16 region after QKV projection

  cvt_kernel<<<NX / 8 / 256, 256, 0, stream>>>(x, xb, NX);
  cvt4_kernel<<<dim3(NW / 8 / 256, 4), 256, 0, stream>>>(WQw, WKw, WVw, WOw, wq, NW);

  const float qscale = 0.125f * 1.4426950408889634f;  // softmax scale + log2(e) folded into Q
  // fused QKV projection: [8192,1024] x [3072,1024]^T -> [8192,3072]
  gemm_bt<unsigned short><<<dim3(3 * D / 128, M / 128), 256, 0, stream>>>(
      xb, wq, WQb, WKb, WVb, QKVb, M, 3 * D, D, 1024, qscale);

  attn_kernel<<<2048, 256, 0, stream>>>(QKVb, AOb);

  gemm_bt<float><<<dim3(D / 128, M / 128), 256, 0, stream>>>(
      AOb, wo, WOb, WOb, WOb, out, M, D, D, 0, 1.0f);
}